// Round 3
// baseline (472.938 us; speedup 1.0000x reference)
//
#include <hip/hip_runtime.h>

#define EPSV 1e-5f

typedef __attribute__((ext_vector_type(8))) short short8v;
typedef __attribute__((ext_vector_type(4))) float f32x4;

static __device__ __forceinline__ unsigned short f2bf(float f) {
  unsigned int u = __float_as_uint(f);
  u += 0x7fff + ((u >> 16) & 1);
  return (unsigned short)(u >> 16);
}
static __device__ __forceinline__ float bf2f(unsigned short h) {
  return __uint_as_float(((unsigned int)h) << 16);
}

// ---------------------------------------------------------------------------
// Prep: conv weights -> Wr[t][cc][co][cil] bf16   (t = dy*3+dx, cc = ci/32)
// ---------------------------------------------------------------------------
__global__ __launch_bounds__(256) void prep_convw_kernel(
    const float* __restrict__ cw, unsigned short* __restrict__ Wr)
{
  int idx = blockIdx.x * 256 + threadIdx.x;
  if (idx >= 9 * 8 * 256 * 32) return;
  int cil = idx & 31;
  int rest = idx >> 5;
  int co = rest & 255;
  int tcc = rest >> 8;
  int cc = tcc & 7;
  int t = tcc >> 3;
  int dy = t / 3, dx = t - dy * 3;
  int ci = cc * 32 + cil;
  Wr[idx] = f2bf(cw[((co * 256 + ci) * 3 + dy) * 3 + dx]);
}

// Prep: transpose wq,wk,wv,wo,rec -> wT[m][ci][co] (f32)
__global__ __launch_bounds__(256) void prep_transpose_kernel(
    const float* __restrict__ wq, const float* __restrict__ wk,
    const float* __restrict__ wv, const float* __restrict__ wo,
    const float* __restrict__ rec, float* __restrict__ wT)
{
  int idx = blockIdx.x * 256 + threadIdx.x;
  if (idx >= 5 * 65536) return;
  int m = idx >> 16;
  int e = idx & 65535;
  int ci = e >> 8, co = e & 255;
  const float* src = (m == 0) ? wq : (m == 1) ? wk : (m == 2) ? wv : (m == 3) ? wo : rec;
  wT[idx] = src[co * 256 + ci];
}

// ---------------------------------------------------------------------------
// Prep: x NCHW f32 -> xin NHWC bf16 (LDS transpose per (b,y) row)
// ---------------------------------------------------------------------------
__global__ __launch_bounds__(256) void prep_nhwc_kernel(
    const float* __restrict__ x, unsigned short* __restrict__ xin)
{
  int blk = blockIdx.x;
  int b = blk / 80, y = blk - b * 80;
  __shared__ unsigned short t[80 * 257];
  const float* src = x + (size_t)b * 256 * 6400 + y * 80;
  for (int e = threadIdx.x; e < 80 * 256; e += 256) {
    int c = e / 80;
    int px = e - c * 80;
    t[px * 257 + c] = f2bf(src[(size_t)c * 6400 + px]);
  }
  __syncthreads();
  unsigned short* dst = xin + (size_t)blk * 80 * 256;
  for (int e = threadIdx.x; e < 80 * 32; e += 256) {
    int px = e >> 5;
    int c8 = e & 31;
    short8v v;
#pragma unroll
    for (int j = 0; j < 8; ++j) v[j] = t[px * 257 + c8 * 8 + j];
    *(short8v*)&dst[px * 256 + c8 * 8] = v;
  }
}

// ---------------------------------------------------------------------------
// Conv 3x3 + bias + BN + SiLU -> feat NHWC bf16.
// Block per (b, row): 256 thr, 4 waves = 4 disjoint co-groups (N=64 each).
// Wave M=80 (5 xf), acc[5][4] (80 AGPR). Weights per-lane from L2 (dup=1).
// Wave t-stagger: wave w runs taps (tt+2w)%9 -> cross-wave pipe overlap.
// LDS: double-buffered 3-row input tile, (px>>1)&3 XOR swizzle (conflict-free).
// ---------------------------------------------------------------------------
__global__ __launch_bounds__(256, 3) void conv_kernel(
    const unsigned short* __restrict__ xin,
    const float* __restrict__ convb,
    const float* __restrict__ bn1g, const float* __restrict__ bn1b,
    const float* __restrict__ bn1m, const float* __restrict__ bn1v,
    const unsigned short* __restrict__ Wr,
    unsigned short* __restrict__ feat)
{
  const int blk = blockIdx.x;
  const int b = blk / 80, y = blk - b * 80;
  const int tid = threadIdx.x;
  const int w = tid >> 6, lane = tid & 63;
  const int bq = lane >> 4, r16 = lane & 15;

  // union: staging 2 x 984 slots x 16B = 31488 B;  epilogue 80*264*2 = 42240 B
  __shared__ __align__(16) char lds[42240];

  f32x4 acc[5][4];
#pragma unroll
  for (int i = 0; i < 5; ++i)
#pragma unroll
    for (int j = 0; j < 4; ++j)
      acc[i][j] = (f32x4){0.f, 0.f, 0.f, 0.f};

  // precompute per-lane af byte offsets g[xf*3+dx] (swizzled)
  int g[15];
#pragma unroll
  for (int xf = 0; xf < 5; ++xf)
#pragma unroll
    for (int dx = 0; dx < 3; ++dx) {
      int px = xf * 16 + r16 + dx;
      g[xf * 3 + dx] = ((px * 4 + (bq ^ ((px >> 1) & 3))) << 4);
    }

  const int s0 = tid, s1 = tid + 256, s2 = tid + 512, s3 = tid + 768;
  const bool has3 = (tid < 216);  // 984 slots total

  auto ld_slot = [&](int s, int cc, short8v& r) {
    int row = s / 328;
    int rem = s - row * 328;
    int px = rem >> 2;
    int swz = rem & 3;
    int chunk = swz ^ ((px >> 1) & 3);
    int gy = y + row - 1, gx = px - 1;
    if ((unsigned)gy < 80u && (unsigned)gx < 80u)
      r = *(const short8v*)&xin[(((size_t)(b * 80 + gy)) * 80 + gx) * 256 + cc * 32 + chunk * 8];
    else
      r = (short8v){0, 0, 0, 0, 0, 0, 0, 0};
  };

  short8v st0, st1, st2, st3;
  // prologue: stage cc=0 into buf0
  ld_slot(s0, 0, st0);
  ld_slot(s1, 0, st1);
  ld_slot(s2, 0, st2);
  if (has3) ld_slot(s3, 0, st3);
  *(short8v*)(lds + s0 * 16) = st0;
  *(short8v*)(lds + s1 * 16) = st1;
  *(short8v*)(lds + s2 * 16) = st2;
  if (has3) *(short8v*)(lds + s3 * 16) = st3;
  // preload regs for cc=1
  ld_slot(s0, 1, st0);
  ld_slot(s1, 1, st1);
  ld_slot(s2, 1, st2);
  if (has3) ld_slot(s3, 1, st3);
  __syncthreads();

  const int wlaneoff = (w * 64 + r16) * 32 + bq * 8;  // + cf*512 per cf

  for (int cc = 0; cc < 8; ++cc) {
    const int cur = cc & 1;
    const int nbase = (cur ^ 1) * 15744;
    // write-late: stage regs (data for cc+1) into the other buffer
    if (cc < 7) {
      *(short8v*)(lds + nbase + s0 * 16) = st0;
      *(short8v*)(lds + nbase + s1 * 16) = st1;
      *(short8v*)(lds + nbase + s2 * 16) = st2;
      if (has3) *(short8v*)(lds + nbase + s3 * 16) = st3;
    }
    // issue-early: global loads for cc+2
    if (cc < 6) {
      ld_slot(s0, cc + 2, st0);
      ld_slot(s1, cc + 2, st1);
      ld_slot(s2, cc + 2, st2);
      if (has3) ld_slot(s3, cc + 2, st3);
    }
    const char* buf = lds + cur * 15744;
#pragma unroll
    for (int tt = 0; tt < 9; ++tt) {
      int t = tt + (w << 1);
      t -= (t >= 9) ? 9 : 0;            // per-wave tap stagger
      int dy = (t * 11) >> 5;           // t/3 for t in [0,9)
      int dx = t - dy * 3;
      const unsigned short* wg = Wr + ((size_t)((t * 8 + cc)) << 13) + wlaneoff;
      short8v wf0 = *(const short8v*)&wg[0];
      short8v wf1 = *(const short8v*)&wg[512];
      short8v wf2 = *(const short8v*)&wg[1024];
      short8v wf3 = *(const short8v*)&wg[1536];
      const char* rowbuf = buf + dy * 5248;
      short8v af0 = *(const short8v*)(rowbuf + g[0 * 3 + dx]);
      short8v af1 = *(const short8v*)(rowbuf + g[1 * 3 + dx]);
      short8v af2 = *(const short8v*)(rowbuf + g[2 * 3 + dx]);
      short8v af3 = *(const short8v*)(rowbuf + g[3 * 3 + dx]);
      short8v af4 = *(const short8v*)(rowbuf + g[4 * 3 + dx]);
      __builtin_amdgcn_s_setprio(1);
      acc[0][0] = __builtin_amdgcn_mfma_f32_16x16x32_bf16(af0, wf0, acc[0][0], 0, 0, 0);
      acc[0][1] = __builtin_amdgcn_mfma_f32_16x16x32_bf16(af0, wf1, acc[0][1], 0, 0, 0);
      acc[0][2] = __builtin_amdgcn_mfma_f32_16x16x32_bf16(af0, wf2, acc[0][2], 0, 0, 0);
      acc[0][3] = __builtin_amdgcn_mfma_f32_16x16x32_bf16(af0, wf3, acc[0][3], 0, 0, 0);
      acc[1][0] = __builtin_amdgcn_mfma_f32_16x16x32_bf16(af1, wf0, acc[1][0], 0, 0, 0);
      acc[1][1] = __builtin_amdgcn_mfma_f32_16x16x32_bf16(af1, wf1, acc[1][1], 0, 0, 0);
      acc[1][2] = __builtin_amdgcn_mfma_f32_16x16x32_bf16(af1, wf2, acc[1][2], 0, 0, 0);
      acc[1][3] = __builtin_amdgcn_mfma_f32_16x16x32_bf16(af1, wf3, acc[1][3], 0, 0, 0);
      acc[2][0] = __builtin_amdgcn_mfma_f32_16x16x32_bf16(af2, wf0, acc[2][0], 0, 0, 0);
      acc[2][1] = __builtin_amdgcn_mfma_f32_16x16x32_bf16(af2, wf1, acc[2][1], 0, 0, 0);
      acc[2][2] = __builtin_amdgcn_mfma_f32_16x16x32_bf16(af2, wf2, acc[2][2], 0, 0, 0);
      acc[2][3] = __builtin_amdgcn_mfma_f32_16x16x32_bf16(af2, wf3, acc[2][3], 0, 0, 0);
      acc[3][0] = __builtin_amdgcn_mfma_f32_16x16x32_bf16(af3, wf0, acc[3][0], 0, 0, 0);
      acc[3][1] = __builtin_amdgcn_mfma_f32_16x16x32_bf16(af3, wf1, acc[3][1], 0, 0, 0);
      acc[3][2] = __builtin_amdgcn_mfma_f32_16x16x32_bf16(af3, wf2, acc[3][2], 0, 0, 0);
      acc[3][3] = __builtin_amdgcn_mfma_f32_16x16x32_bf16(af3, wf3, acc[3][3], 0, 0, 0);
      acc[4][0] = __builtin_amdgcn_mfma_f32_16x16x32_bf16(af4, wf0, acc[4][0], 0, 0, 0);
      acc[4][1] = __builtin_amdgcn_mfma_f32_16x16x32_bf16(af4, wf1, acc[4][1], 0, 0, 0);
      acc[4][2] = __builtin_amdgcn_mfma_f32_16x16x32_bf16(af4, wf2, acc[4][2], 0, 0, 0);
      acc[4][3] = __builtin_amdgcn_mfma_f32_16x16x32_bf16(af4, wf3, acc[4][3], 0, 0, 0);
      __builtin_amdgcn_s_setprio(0);
    }
    __syncthreads();
  }

  // epilogue: bias + BN + SiLU, stage row to LDS, coalesced NHWC write
  unsigned short* ep = (unsigned short*)lds;  // [xx*264 + co]
#pragma unroll
  for (int cf = 0; cf < 4; ++cf) {
    int co = w * 64 + cf * 16 + r16;
    float s  = bn1g[co] / sqrtf(bn1v[co] + EPSV);
    float sh = bn1b[co] - bn1m[co] * s;
    float cb = convb[co];
#pragma unroll
    for (int xf = 0; xf < 5; ++xf) {
#pragma unroll
      for (int r = 0; r < 4; ++r) {
        int xx = xf * 16 + bq * 4 + r;  // D row = 4*(lane>>4)+reg (m89)
        float v = (acc[xf][cf][r] + cb) * s + sh;
        v = v / (1.f + __expf(-v));     // SiLU
        ep[xx * 264 + co] = f2bf(v);
      }
    }
  }
  __syncthreads();
  unsigned short* fout = feat + (size_t)((b * 80 + y) * 80) * 256;
  for (int i2 = tid; i2 < 2560; i2 += 256) {
    int xx = i2 >> 5;
    int c8 = (i2 & 31) << 3;
    *(short8v*)&fout[xx * 256 + c8] = *(const short8v*)&ep[xx * 264 + c8];
  }
}

// ---------------------------------------------------------------------------
// roi_align 1x1 (S=4, torchvision semantics). Block per node, thread per ch.
// ---------------------------------------------------------------------------
__global__ __launch_bounds__(256) void roi_kernel(
    const unsigned short* __restrict__ feat,
    const float* __restrict__ boxes,
    float* __restrict__ nodes)
{
  const int n = blockIdx.x;
  const int b = n >> 5;
  const int c = threadIdx.x;
  const float* bx = boxes + n * 4;
  float x1 = bx[0] * 79.f, y1 = bx[1] * 79.f, x2 = bx[2] * 79.f, y2 = bx[3] * 79.f;
  float rw = fmaxf(x2 - x1, 1.f), rh = fmaxf(y2 - y1, 1.f);
  const unsigned short* fb = feat + (size_t)b * 80 * 80 * 256;
  float acc = 0.f;
#pragma unroll
  for (int sy = 0; sy < 4; ++sy) {
    float yy = y1 + (sy + 0.5f) * 0.25f * rh;
#pragma unroll
    for (int sx = 0; sx < 4; ++sx) {
      float xx = x1 + (sx + 0.5f) * 0.25f * rw;
      if (yy < -1.f || yy > 80.f || xx < -1.f || xx > 80.f) continue;
      float yc = fminf(fmaxf(yy, 0.f), 79.f);
      float xc = fminf(fmaxf(xx, 0.f), 79.f);
      float y0 = floorf(yc), x0f = floorf(xc);
      int y0i = (int)y0, x0i = (int)x0f;
      int y1i = min(y0i + 1, 79), x1i = min(x0i + 1, 79);
      float ly = yc - y0, lx = xc - x0f;
      float hy = 1.f - ly, hx = 1.f - lx;
      float v00 = bf2f(fb[((y0i * 80) + x0i) * 256 + c]);
      float v01 = bf2f(fb[((y0i * 80) + x1i) * 256 + c]);
      float v10 = bf2f(fb[((y1i * 80) + x0i) * 256 + c]);
      float v11 = bf2f(fb[((y1i * 80) + x1i) * 256 + c]);
      acc += hy * hx * v00 + hy * lx * v01 + ly * hx * v10 + ly * lx * v11;
    }
  }
  nodes[n * 256 + c] = acc * 0.0625f;
}

// ---------------------------------------------------------------------------
// q,k,v projections. Block handles 8 nodes; thread = output channel.
// ---------------------------------------------------------------------------
__global__ __launch_bounds__(256) void qkv_kernel(
    const float* __restrict__ nodes, const float* __restrict__ wT,
    const float* __restrict__ bq, const float* __restrict__ bk,
    const float* __restrict__ bv,
    float* __restrict__ q, float* __restrict__ k, float* __restrict__ v)
{
  const int blk = blockIdx.x;
  const int co = threadIdx.x;
  __shared__ float nd[8][256];
  for (int i = threadIdx.x; i < 2048; i += 256)
    nd[i >> 8][i & 255] = nodes[blk * 2048 + i];
  __syncthreads();
  float aq[8] = {0,0,0,0,0,0,0,0};
  float ak[8] = {0,0,0,0,0,0,0,0};
  float av[8] = {0,0,0,0,0,0,0,0};
  const float* wqT = wT;
  const float* wkT = wT + 65536;
  const float* wvT = wT + 131072;
  for (int ci = 0; ci < 256; ++ci) {
    float wq_ = wqT[ci * 256 + co];
    float wk_ = wkT[ci * 256 + co];
    float wv_ = wvT[ci * 256 + co];
#pragma unroll
    for (int r = 0; r < 8; ++r) {
      float nv = nd[r][ci];
      aq[r] += nv * wq_;
      ak[r] += nv * wk_;
      av[r] += nv * wv_;
    }
  }
  float bq_ = bq[co], bk_ = bk[co], bv_ = bv[co];
#pragma unroll
  for (int r = 0; r < 8; ++r) {
    int n = blk * 8 + r;
    q[n * 256 + co] = aq[r] + bq_;
    k[n * 256 + co] = ak[r] + bk_;
    v[n * 256 + co] = av[r] + bv_;
  }
}

// ---------------------------------------------------------------------------
// Attention over all 512 nodes + out-proj + residual + LayerNorm.
// Block per query node i.
// ---------------------------------------------------------------------------
__global__ __launch_bounds__(256) void attn_kernel(
    const float* __restrict__ q, const float* __restrict__ k,
    const float* __restrict__ v, const float* __restrict__ nodes,
    const float* __restrict__ woT, const float* __restrict__ bo,
    const float* __restrict__ lng, const float* __restrict__ lnb,
    const float* __restrict__ scale_p, float* __restrict__ enh)
{
  const int i = blockIdx.x;
  const int tid = threadIdx.x;
  const float scale = scale_p[0];
  __shared__ __align__(16) float qs[256];
  __shared__ float sc[512 * 8];
  __shared__ float msgs[256];
  __shared__ float r1[4], r2[4];
  qs[tid] = q[i * 256 + tid];
  __syncthreads();
  {
    const int h = tid & 7, jl = tid >> 3;
    for (int jc = 0; jc < 16; ++jc) {
      int j = jc * 32 + jl;
      const f32x4* kr = (const f32x4*)(k + (size_t)j * 256 + h * 32);
      const f32x4* qr = (const f32x4*)(qs + h * 32);
      float s = 0.f;
#pragma unroll
      for (int d4 = 0; d4 < 8; ++d4) {
        f32x4 kv = kr[d4], qv = qr[d4];
        s += kv.x * qv.x + kv.y * qv.y + kv.z * qv.z + kv.w * qv.w;
      }
      sc[j * 8 + h] = s * scale;
    }
  }
  __syncthreads();
  const int hh = tid >> 5, l32 = tid & 31;
  float mx = -1e30f;
  for (int j = l32; j < 512; j += 32) mx = fmaxf(mx, sc[j * 8 + hh]);
#pragma unroll
  for (int o = 1; o < 32; o <<= 1) mx = fmaxf(mx, __shfl_xor(mx, o, 32));
  float sum = 0.f;
  for (int j = l32; j < 512; j += 32) {
    float e = __expf(sc[j * 8 + hh] - mx);
    sc[j * 8 + hh] = e;
    sum += e;
  }
#pragma unroll
  for (int o = 1; o < 32; o <<= 1) sum += __shfl_xor(sum, o, 32);
  float inv = 1.f / sum;
  __syncthreads();
  {
    const int d = l32;
    float m = 0.f;
    for (int j = 0; j < 512; ++j)
      m += sc[j * 8 + hh] * v[(size_t)j * 256 + hh * 32 + d];
    msgs[hh * 32 + d] = m * inv;
  }
  __syncthreads();
  const int co = tid;
  float yv = nodes[i * 256 + co] + bo[co];
  for (int ci = 0; ci < 256; ++ci)
    yv += msgs[ci] * woT[ci * 256 + co];
  float s1 = yv, s2 = yv * yv;
#pragma unroll
  for (int o = 1; o < 64; o <<= 1) { s1 += __shfl_xor(s1, o); s2 += __shfl_xor(s2, o); }
  if ((tid & 63) == 0) { r1[tid >> 6] = s1; r2[tid >> 6] = s2; }
  __syncthreads();
  float S1 = r1[0] + r1[1] + r1[2] + r1[3];
  float S2 = r2[0] + r2[1] + r2[2] + r2[3];
  float mu = S1 * (1.f / 256.f);
  float var = S2 * (1.f / 256.f) - mu * mu;
  float nrm = (yv - mu) * rsqrtf(var + EPSV);
  enh[i * 256 + co] = nrm * lng[co] + lnb[co];
}

// ---------------------------------------------------------------------------
// Per-batch pooling + rec 1x1 conv + BN2 -> yfin[b][c]. Block per batch.
// ---------------------------------------------------------------------------
__global__ __launch_bounds__(256) void final_kernel(
    const float* __restrict__ enh, const float* __restrict__ recT,
    const float* __restrict__ recb,
    const float* __restrict__ bn2g, const float* __restrict__ bn2b,
    const float* __restrict__ bn2m, const float* __restrict__ bn2v,
    float* __restrict__ yfin)
{
  const int b = blockIdx.x;
  const int tid = threadIdx.x;
  const int wv = tid >> 6, l = tid & 63;
  __shared__ float rm[32], wts[32], wgt[256];
  for (int kk = wv; kk < 32; kk += 4) {
    const float* er = enh + (size_t)(b * 32 + kk) * 256;
    float s = er[l] + er[l + 64] + er[l + 128] + er[l + 192];
#pragma unroll
    for (int o = 1; o < 64; o <<= 1) s += __shfl_xor(s, o);
    if (l == 0) rm[kk] = s * (1.f / 256.f);
  }
  __syncthreads();
  if (tid < 32) {
    float m = rm[tid];
    float mx = m;
#pragma unroll
    for (int o = 1; o < 32; o <<= 1) mx = fmaxf(mx, __shfl_xor(mx, o, 32));
    float e = __expf(m - mx);
    float sm = e;
#pragma unroll
    for (int o = 1; o < 32; o <<= 1) sm += __shfl_xor(sm, o, 32);
    wts[tid] = e / sm;
  }
  __syncthreads();
  float wsum = 0.f;
  for (int kk = 0; kk < 32; ++kk)
    wsum += enh[(size_t)(b * 32 + kk) * 256 + tid] * wts[kk];
  wgt[tid] = wsum;
  __syncthreads();
  const int co = tid;
  float yv = recb[co];
  for (int ci = 0; ci < 256; ++ci)
    yv += wgt[ci] * recT[ci * 256 + co];
  float s = bn2g[co] / sqrtf(bn2v[co] + EPSV);
  yfin[b * 256 + co] = yv * s + (bn2b[co] - bn2m[co] * s);
}

// ---------------------------------------------------------------------------
// out = x + yfin[b][c] broadcast
// ---------------------------------------------------------------------------
__global__ __launch_bounds__(256) void add_kernel(
    const float* __restrict__ x, const float* __restrict__ yfin,
    float* __restrict__ out)
{
  const size_t tot = (size_t)26214400 / 4;
  for (size_t idx = (size_t)blockIdx.x * 256 + threadIdx.x; idx < tot;
       idx += (size_t)gridDim.x * 256) {
    size_t e = idx * 4;
    int bc = (int)(e / 6400);
    f32x4 xv = ((const f32x4*)x)[idx];
    float a = yfin[bc];
    xv.x += a; xv.y += a; xv.z += a; xv.w += a;
    ((f32x4*)out)[idx] = xv;
  }
}

extern "C" void kernel_launch(void* const* d_in, const int* in_sizes, int n_in,
                              void* d_out, int out_size, void* d_ws, size_t ws_size,
                              hipStream_t stream)
{
  const float* x      = (const float*)d_in[0];
  const float* boxes  = (const float*)d_in[1];
  const float* conv_w = (const float*)d_in[2];
  const float* conv_b = (const float*)d_in[3];
  const float* bn1g   = (const float*)d_in[4];
  const float* bn1b   = (const float*)d_in[5];
  const float* bn1m   = (const float*)d_in[6];
  const float* bn1v   = (const float*)d_in[7];
  const float* wq     = (const float*)d_in[8];
  const float* bq     = (const float*)d_in[9];
  const float* wk     = (const float*)d_in[10];
  const float* bkp    = (const float*)d_in[11];
  const float* wv     = (const float*)d_in[12];
  const float* bv     = (const float*)d_in[13];
  const float* scale  = (const float*)d_in[14];
  const float* wo     = (const float*)d_in[15];
  const float* bo     = (const float*)d_in[16];
  const float* lng    = (const float*)d_in[17];
  const float* lnb    = (const float*)d_in[18];
  const float* rec_w  = (const float*)d_in[19];
  const float* rec_b  = (const float*)d_in[20];
  const float* bn2g   = (const float*)d_in[21];
  const float* bn2b   = (const float*)d_in[22];
  const float* bn2m   = (const float*)d_in[23];
  const float* bn2v   = (const float*)d_in[24];
  float* out = (float*)d_out;

  char* ws = (char*)d_ws;
  unsigned short* Wr   = (unsigned short*)(ws);                       // 1,179,648 B
  unsigned short* feat = (unsigned short*)(ws + 1179648);             // 52,428,800 B
  float* wT    = (float*)(ws + 53608448);                             // 1,310,720 B
  float* nodes = (float*)(ws + 54919168);
  float* qb    = nodes + 131072;
  float* kb    = qb + 131072;
  float* vb    = kb + 131072;
  float* enh   = vb + 131072;
  float* yfin  = enh + 131072;

  // xin (NHWC bf16, 52.4 MB) lives in d_out scratch — fully consumed by conv
  // before add_kernel overwrites d_out at the end. Deterministic each call.
  unsigned short* xin = (unsigned short*)d_out;

  hipLaunchKernelGGL(prep_convw_kernel, dim3(2304), dim3(256), 0, stream, conv_w, Wr);
  hipLaunchKernelGGL(prep_transpose_kernel, dim3(1280), dim3(256), 0, stream,
                     wq, wk, wv, wo, rec_w, wT);
  hipLaunchKernelGGL(prep_nhwc_kernel, dim3(1280), dim3(256), 0, stream, x, xin);
  hipLaunchKernelGGL(conv_kernel, dim3(1280), dim3(256), 0, stream,
                     xin, conv_b, bn1g, bn1b, bn1m, bn1v, Wr, feat);
  hipLaunchKernelGGL(roi_kernel, dim3(512), dim3(256), 0, stream, feat, boxes, nodes);
  hipLaunchKernelGGL(qkv_kernel, dim3(64), dim3(256), 0, stream,
                     nodes, wT, bq, bkp, bv, qb, kb, vb);
  hipLaunchKernelGGL(attn_kernel, dim3(512), dim3(256), 0, stream,
                     qb, kb, vb, nodes, wT + 3 * 65536, bo, lng, lnb, scale, enh);
  hipLaunchKernelGGL(final_kernel, dim3(16), dim3(256), 0, stream,
                     enh, wT + 4 * 65536, rec_b, bn2g, bn2b, bn2m, bn2v, yfin);
  hipLaunchKernelGGL(add_kernel, dim3(2048), dim3(256), 0, stream, x, yfin, out);
}

// Round 4
// 291.075 us; speedup vs baseline: 1.6248x; 1.6248x over previous
//
#include <hip/hip_runtime.h>

#define EPSV 1e-5f

typedef __attribute__((ext_vector_type(8))) short short8v;
typedef __attribute__((ext_vector_type(4))) float f32x4;

static __device__ __forceinline__ unsigned short f2bf(float f) {
  unsigned int u = __float_as_uint(f);
  u += 0x7fff + ((u >> 16) & 1);
  return (unsigned short)(u >> 16);
}
static __device__ __forceinline__ float bf2f(unsigned short h) {
  return __uint_as_float(((unsigned int)h) << 16);
}

// async global->LDS 16B: dest = wave-uniform base + lane*16 (linear)
static __device__ __forceinline__ void glds16(const void* g, void* l) {
  __builtin_amdgcn_global_load_lds(
      (const __attribute__((address_space(1))) void*)g,
      (__attribute__((address_space(3))) void*)l, 16, 0, 0);
}

// ---------------------------------------------------------------------------
// Prep: conv weights -> Wr[t][cc][co][cil] bf16 (t = dy*3+dx, cc = ci/32)
// Also zeroes the 1KB zpad scratch used as OOB source for global_load_lds.
// ---------------------------------------------------------------------------
__global__ __launch_bounds__(256) void prep_convw_kernel(
    const float* __restrict__ cw, unsigned short* __restrict__ Wr,
    float* __restrict__ zpad)
{
  if (blockIdx.x == 0) zpad[threadIdx.x] = 0.f;
  int idx = blockIdx.x * 256 + threadIdx.x;
  if (idx >= 9 * 8 * 256 * 32) return;
  int cil = idx & 31;
  int rest = idx >> 5;
  int co = rest & 255;
  int tcc = rest >> 8;
  int cc = tcc & 7;
  int t = tcc >> 3;
  int dy = t / 3, dx = t - dy * 3;
  int ci = cc * 32 + cil;
  Wr[idx] = f2bf(cw[((co * 256 + ci) * 3 + dy) * 3 + dx]);
}

// Prep: transpose wq,wk,wv,wo,rec -> wT[m][ci][co] (f32)
__global__ __launch_bounds__(256) void prep_transpose_kernel(
    const float* __restrict__ wq, const float* __restrict__ wk,
    const float* __restrict__ wv, const float* __restrict__ wo,
    const float* __restrict__ rec, float* __restrict__ wT)
{
  int idx = blockIdx.x * 256 + threadIdx.x;
  if (idx >= 5 * 65536) return;
  int m = idx >> 16;
  int e = idx & 65535;
  int ci = e >> 8, co = e & 255;
  const float* src = (m == 0) ? wq : (m == 1) ? wk : (m == 2) ? wv : (m == 3) ? wo : rec;
  wT[idx] = src[co * 256 + ci];
}

// ---------------------------------------------------------------------------
// Prep: x NCHW f32 -> xin NHWC bf16 (LDS transpose per (b,y) row)
// ---------------------------------------------------------------------------
__global__ __launch_bounds__(256) void prep_nhwc_kernel(
    const float* __restrict__ x, unsigned short* __restrict__ xin)
{
  int blk = blockIdx.x;
  int b = blk / 80, y = blk - b * 80;
  __shared__ unsigned short t[80 * 257];
  const float* src = x + (size_t)b * 256 * 6400 + y * 80;
  for (int e = threadIdx.x; e < 80 * 256; e += 256) {
    int c = e / 80;
    int px = e - c * 80;
    t[px * 257 + c] = f2bf(src[(size_t)c * 6400 + px]);
  }
  __syncthreads();
  unsigned short* dst = xin + (size_t)blk * 80 * 256;
  for (int e = threadIdx.x; e < 80 * 32; e += 256) {
    int px = e >> 5;
    int c8 = e & 31;
    short8v v;
#pragma unroll
    for (int j = 0; j < 8; ++j) v[j] = t[px * 257 + c8 * 8 + j];
    *(short8v*)&dst[px * 256 + c8 * 8] = v;
  }
}

// ---------------------------------------------------------------------------
// Conv 3x3 + bias + BN + SiLU -> feat NHWC bf16.
// Block: 512 thr / 8 waves = 4(rows) x 2(co64).  Tile M=320 px, N=128 co.
// K-step = (cc,t): weights staged ONCE per block per step via global_load_lds
// (double-buffered 8KB), input rows staged per cc (double-buffered 32KB).
// All LDS XOR-swizzled via pre-swizzled global source (linear gl_lds dest).
// One barrier per t-step; 20 MFMA per wave between barriers.
// ---------------------------------------------------------------------------
__global__ __launch_bounds__(512, 2) void conv_kernel(
    const unsigned short* __restrict__ xin,
    const float* __restrict__ convb,
    const float* __restrict__ bn1g, const float* __restrict__ bn1b,
    const float* __restrict__ bn1m, const float* __restrict__ bn1v,
    const unsigned short* __restrict__ Wr,
    const unsigned short* __restrict__ zpad,
    unsigned short* __restrict__ feat)
{
  const int bid = blockIdx.x;
  const int orig = (bid & 7) * 80 + (bid >> 3);   // XCD-bijective (640 % 8 == 0)
  const int b = orig / 40;
  const int r = orig - b * 40;
  const int yq = (r >> 1) * 4;
  const int coh = r & 1;
  const int tid = threadIdx.x;
  const int w = tid >> 6, lane = tid & 63;
  const int bq = lane >> 4, r16 = lane & 15;
  const int wr = w >> 1, wc = w & 1;

  // LDS: IN0@0 IN1@32768 (2048 slots x16B each), W0@65536 W1@73728 (8KB each)
  // epilogue union: [4][80][136] shorts = 87040 B
  __shared__ __align__(16) char lds[87040];
  const int IN0 = 0, IN1 = 32768, W0 = 65536, W1 = 73728;

  f32x4 acc[5][4];
#pragma unroll
  for (int i = 0; i < 5; ++i)
#pragma unroll
    for (int j = 0; j < 4; ++j)
      acc[i][j] = (f32x4){0.f, 0.f, 0.f, 0.f};

  // input staging source precompute: 4 parts, slot s = tid + p*512
  // slot s -> row6 = s/328, px = (s%328)>>2, swz = s&3, chunk = swz^((px>>1)&3)
  const unsigned short* isrc[4];
#pragma unroll
  for (int p = 0; p < 4; ++p) {
    int s = tid + (p << 9);
    int row6 = s / 328;
    int rem = s - row6 * 328;
    int px = rem >> 2;
    int qs = rem & 3;
    int chunk = qs ^ ((px >> 1) & 3);
    int gy = yq + row6 - 1, gx = px - 1;
    bool ok = (row6 < 6) && ((unsigned)gy < 80u) && ((unsigned)gx < 80u);
    isrc[p] = ok ? (xin + (((size_t)(b * 80 + gy)) * 80 + gx) * 256 + chunk * 8)
                 : zpad;                      // OOB -> zeros (1KB zeroed pad)
  }

  // weight staging source precompute: slot tid -> co = tid>>2, chunk swizzled
  const int wco = tid >> 2;
  const int wchunk = (tid & 3) ^ ((wco >> 1) & 3);
  const unsigned short* wsrc0 = Wr + ((coh << 7) + wco) * 32 + wchunk * 8;

  // swizzled read offsets
  int afo[3];
#pragma unroll
  for (int dx = 0; dx < 3; ++dx)
    afo[dx] = (r16 + dx) * 64 + ((bq ^ (((r16 + dx) >> 1) & 3)) << 4);
  const int wfo = (wc * 64 + r16) * 64 + ((bq ^ ((r16 >> 1) & 3)) << 4);

  // prologue: stage input cc=0 (all 4 parts) + W step0
  {
#pragma unroll
    for (int p = 0; p < 4; ++p)
      glds16(isrc[p], lds + IN0 + (((p << 9) + (w << 6)) << 4));
    glds16(wsrc0, lds + W0 + ((w << 6) << 4));
  }
  __syncthreads();

  for (int cc = 0; cc < 8; ++cc) {
    const char* inb = lds + ((cc & 1) ? IN1 : IN0);
    char* innx = lds + ((cc & 1) ? IN0 : IN1);
#pragma unroll
    for (int t = 0; t < 9; ++t) {
      const int step = cc * 9 + t;
      const char* wb = lds + ((step & 1) ? W1 : W0);
      char* wbn = lds + ((step & 1) ? W0 : W1);
      if (step < 71) {
        const int nt = (t == 8) ? 0 : t + 1;
        const int ncc = (t == 8) ? cc + 1 : cc;
        glds16(wsrc0 + ((size_t)(nt * 8 + ncc) << 13), wbn + ((w << 6) << 4));
      }
      if (t < 4 && cc < 7)
        glds16(isrc[t] + (cc + 1) * 32, innx + (((t << 9) + (w << 6)) << 4));
      const int dy = (t * 11) >> 5;
      const int dx = t - dy * 3;
      short8v wf0 = *(const short8v*)(wb + wfo);
      short8v wf1 = *(const short8v*)(wb + wfo + 1024);
      short8v wf2 = *(const short8v*)(wb + wfo + 2048);
      short8v wf3 = *(const short8v*)(wb + wfo + 3072);
      const char* pa = inb + (wr + dy) * 5248 + afo[dx];
      short8v af0 = *(const short8v*)(pa);
      short8v af1 = *(const short8v*)(pa + 1024);
      short8v af2 = *(const short8v*)(pa + 2048);
      short8v af3 = *(const short8v*)(pa + 3072);
      short8v af4 = *(const short8v*)(pa + 4096);
      acc[0][0] = __builtin_amdgcn_mfma_f32_16x16x32_bf16(af0, wf0, acc[0][0], 0, 0, 0);
      acc[0][1] = __builtin_amdgcn_mfma_f32_16x16x32_bf16(af0, wf1, acc[0][1], 0, 0, 0);
      acc[0][2] = __builtin_amdgcn_mfma_f32_16x16x32_bf16(af0, wf2, acc[0][2], 0, 0, 0);
      acc[0][3] = __builtin_amdgcn_mfma_f32_16x16x32_bf16(af0, wf3, acc[0][3], 0, 0, 0);
      acc[1][0] = __builtin_amdgcn_mfma_f32_16x16x32_bf16(af1, wf0, acc[1][0], 0, 0, 0);
      acc[1][1] = __builtin_amdgcn_mfma_f32_16x16x32_bf16(af1, wf1, acc[1][1], 0, 0, 0);
      acc[1][2] = __builtin_amdgcn_mfma_f32_16x16x32_bf16(af1, wf2, acc[1][2], 0, 0, 0);
      acc[1][3] = __builtin_amdgcn_mfma_f32_16x16x32_bf16(af1, wf3, acc[1][3], 0, 0, 0);
      acc[2][0] = __builtin_amdgcn_mfma_f32_16x16x32_bf16(af2, wf0, acc[2][0], 0, 0, 0);
      acc[2][1] = __builtin_amdgcn_mfma_f32_16x16x32_bf16(af2, wf1, acc[2][1], 0, 0, 0);
      acc[2][2] = __builtin_amdgcn_mfma_f32_16x16x32_bf16(af2, wf2, acc[2][2], 0, 0, 0);
      acc[2][3] = __builtin_amdgcn_mfma_f32_16x16x32_bf16(af2, wf3, acc[2][3], 0, 0, 0);
      acc[3][0] = __builtin_amdgcn_mfma_f32_16x16x32_bf16(af3, wf0, acc[3][0], 0, 0, 0);
      acc[3][1] = __builtin_amdgcn_mfma_f32_16x16x32_bf16(af3, wf1, acc[3][1], 0, 0, 0);
      acc[3][2] = __builtin_amdgcn_mfma_f32_16x16x32_bf16(af3, wf2, acc[3][2], 0, 0, 0);
      acc[3][3] = __builtin_amdgcn_mfma_f32_16x16x32_bf16(af3, wf3, acc[3][3], 0, 0, 0);
      acc[4][0] = __builtin_amdgcn_mfma_f32_16x16x32_bf16(af4, wf0, acc[4][0], 0, 0, 0);
      acc[4][1] = __builtin_amdgcn_mfma_f32_16x16x32_bf16(af4, wf1, acc[4][1], 0, 0, 0);
      acc[4][2] = __builtin_amdgcn_mfma_f32_16x16x32_bf16(af4, wf2, acc[4][2], 0, 0, 0);
      acc[4][3] = __builtin_amdgcn_mfma_f32_16x16x32_bf16(af4, wf3, acc[4][3], 0, 0, 0);
      __syncthreads();
    }
  }

  // epilogue: bias + BN + SiLU -> ep[4][80][136] shorts -> coalesced NHWC
  unsigned short* ep = (unsigned short*)lds;
#pragma unroll
  for (int cf = 0; cf < 4; ++cf) {
    int col = wc * 64 + cf * 16 + r16;       // within 128
    int cog = (coh << 7) + col;
    float s  = bn1g[cog] / sqrtf(bn1v[cog] + EPSV);
    float sh = bn1b[cog] - bn1m[cog] * s;
    float cb = convb[cog];
#pragma unroll
    for (int xf = 0; xf < 5; ++xf) {
#pragma unroll
      for (int rg = 0; rg < 4; ++rg) {
        int px = xf * 16 + bq * 4 + rg;      // D row = 4*(lane>>4)+reg (m89)
        float v = (acc[xf][cf][rg] + cb) * s + sh;
        v = v / (1.f + __expf(-v));          // SiLU
        ep[(wr * 80 + px) * 136 + col] = f2bf(v);
      }
    }
  }
  __syncthreads();
  unsigned short* fout = feat + ((size_t)(b * 80 + yq) * 80) * 256 + (coh << 7);
  for (int i2 = tid; i2 < 5120; i2 += 512) {
    int row = i2 / 1280;
    int rem = i2 - row * 1280;
    int px = rem >> 4;
    int c16 = rem & 15;
    *(short8v*)&fout[(row * 80 + px) * 256 + (c16 << 3)] =
        *(const short8v*)&ep[(row * 80 + px) * 136 + (c16 << 3)];
  }
}

// ---------------------------------------------------------------------------
// Fused roi_align (1x1, S=4) + q,k,v projections. Block per node.
// ---------------------------------------------------------------------------
__global__ __launch_bounds__(256) void roi_qkv_kernel(
    const unsigned short* __restrict__ feat,
    const float* __restrict__ boxes, const float* __restrict__ wT,
    const float* __restrict__ bq, const float* __restrict__ bk,
    const float* __restrict__ bv,
    float* __restrict__ nodes, float* __restrict__ q,
    float* __restrict__ k, float* __restrict__ v)
{
  const int n = blockIdx.x;
  const int b = n >> 5;
  const int c = threadIdx.x;
  __shared__ float nd[256];
  const float* bx = boxes + n * 4;
  float x1 = bx[0] * 79.f, y1 = bx[1] * 79.f, x2 = bx[2] * 79.f, y2 = bx[3] * 79.f;
  float rw = fmaxf(x2 - x1, 1.f), rh = fmaxf(y2 - y1, 1.f);
  const unsigned short* fb = feat + (size_t)b * 80 * 80 * 256;
  float acc = 0.f;
#pragma unroll
  for (int sy = 0; sy < 4; ++sy) {
    float yy = y1 + (sy + 0.5f) * 0.25f * rh;
#pragma unroll
    for (int sx = 0; sx < 4; ++sx) {
      float xx = x1 + (sx + 0.5f) * 0.25f * rw;
      if (yy < -1.f || yy > 80.f || xx < -1.f || xx > 80.f) continue;
      float yc = fminf(fmaxf(yy, 0.f), 79.f);
      float xc = fminf(fmaxf(xx, 0.f), 79.f);
      float y0 = floorf(yc), x0f = floorf(xc);
      int y0i = (int)y0, x0i = (int)x0f;
      int y1i = min(y0i + 1, 79), x1i = min(x0i + 1, 79);
      float ly = yc - y0, lx = xc - x0f;
      float hy = 1.f - ly, hx = 1.f - lx;
      float v00 = bf2f(fb[((y0i * 80) + x0i) * 256 + c]);
      float v01 = bf2f(fb[((y0i * 80) + x1i) * 256 + c]);
      float v10 = bf2f(fb[((y1i * 80) + x0i) * 256 + c]);
      float v11 = bf2f(fb[((y1i * 80) + x1i) * 256 + c]);
      acc += hy * hx * v00 + hy * lx * v01 + ly * hx * v10 + ly * lx * v11;
    }
  }
  float val = acc * 0.0625f;
  nodes[n * 256 + c] = val;
  nd[c] = val;
  __syncthreads();
  float aq = 0.f, ak = 0.f, av = 0.f;
  const float* wqT = wT;
  const float* wkT = wT + 65536;
  const float* wvT = wT + 131072;
#pragma unroll 4
  for (int ci = 0; ci < 256; ++ci) {
    float nv = nd[ci];
    aq += nv * wqT[ci * 256 + c];
    ak += nv * wkT[ci * 256 + c];
    av += nv * wvT[ci * 256 + c];
  }
  q[n * 256 + c] = aq + bq[c];
  k[n * 256 + c] = ak + bk[c];
  v[n * 256 + c] = av + bv[c];
}

// ---------------------------------------------------------------------------
// Attention over all 512 nodes + out-proj + residual + LayerNorm.
// Block per query node i.
// ---------------------------------------------------------------------------
__global__ __launch_bounds__(256) void attn_kernel(
    const float* __restrict__ q, const float* __restrict__ k,
    const float* __restrict__ v, const float* __restrict__ nodes,
    const float* __restrict__ woT, const float* __restrict__ bo,
    const float* __restrict__ lng, const float* __restrict__ lnb,
    const float* __restrict__ scale_p, float* __restrict__ enh)
{
  const int i = blockIdx.x;
  const int tid = threadIdx.x;
  const float scale = scale_p[0];
  __shared__ __align__(16) float qs[256];
  __shared__ float sc[512 * 8];
  __shared__ float msgs[256];
  __shared__ float r1[4], r2[4];
  qs[tid] = q[i * 256 + tid];
  __syncthreads();
  {
    const int h = tid & 7, jl = tid >> 3;
    for (int jc = 0; jc < 16; ++jc) {
      int j = jc * 32 + jl;
      const f32x4* kr = (const f32x4*)(k + (size_t)j * 256 + h * 32);
      const f32x4* qr = (const f32x4*)(qs + h * 32);
      float s = 0.f;
#pragma unroll
      for (int d4 = 0; d4 < 8; ++d4) {
        f32x4 kv = kr[d4], qv = qr[d4];
        s += kv.x * qv.x + kv.y * qv.y + kv.z * qv.z + kv.w * qv.w;
      }
      sc[j * 8 + h] = s * scale;
    }
  }
  __syncthreads();
  const int hh = tid >> 5, l32 = tid & 31;
  float mx = -1e30f;
  for (int j = l32; j < 512; j += 32) mx = fmaxf(mx, sc[j * 8 + hh]);
#pragma unroll
  for (int o = 1; o < 32; o <<= 1) mx = fmaxf(mx, __shfl_xor(mx, o, 32));
  float sum = 0.f;
  for (int j = l32; j < 512; j += 32) {
    float e = __expf(sc[j * 8 + hh] - mx);
    sc[j * 8 + hh] = e;
    sum += e;
  }
#pragma unroll
  for (int o = 1; o < 32; o <<= 1) sum += __shfl_xor(sum, o, 32);
  float inv = 1.f / sum;
  __syncthreads();
  {
    const int d = l32;
    float m = 0.f;
    for (int j = 0; j < 512; ++j)
      m += sc[j * 8 + hh] * v[(size_t)j * 256 + hh * 32 + d];
    msgs[hh * 32 + d] = m * inv;
  }
  __syncthreads();
  const int co = tid;
  float yv = nodes[i * 256 + co] + bo[co];
  for (int ci = 0; ci < 256; ++ci)
    yv += msgs[ci] * woT[ci * 256 + co];
  float s1 = yv, s2 = yv * yv;
#pragma unroll
  for (int o = 1; o < 64; o <<= 1) { s1 += __shfl_xor(s1, o); s2 += __shfl_xor(s2, o); }
  if ((tid & 63) == 0) { r1[tid >> 6] = s1; r2[tid >> 6] = s2; }
  __syncthreads();
  float S1 = r1[0] + r1[1] + r1[2] + r1[3];
  float S2 = r2[0] + r2[1] + r2[2] + r2[3];
  float mu = S1 * (1.f / 256.f);
  float var = S2 * (1.f / 256.f) - mu * mu;
  float nrm = (yv - mu) * rsqrtf(var + EPSV);
  enh[i * 256 + co] = nrm * lng[co] + lnb[co];
}

// ---------------------------------------------------------------------------
// Per-batch pooling + rec 1x1 conv + BN2 -> yfin[b][c]. Block per batch.
// ---------------------------------------------------------------------------
__global__ __launch_bounds__(256) void final_kernel(
    const float* __restrict__ enh, const float* __restrict__ recT,
    const float* __restrict__ recb,
    const float* __restrict__ bn2g, const float* __restrict__ bn2b,
    const float* __restrict__ bn2m, const float* __restrict__ bn2v,
    float* __restrict__ yfin)
{
  const int b = blockIdx.x;
  const int tid = threadIdx.x;
  const int wv = tid >> 6, l = tid & 63;
  __shared__ float rm[32], wts[32], wgt[256];
  for (int kk = wv; kk < 32; kk += 4) {
    const float* er = enh + (size_t)(b * 32 + kk) * 256;
    float s = er[l] + er[l + 64] + er[l + 128] + er[l + 192];
#pragma unroll
    for (int o = 1; o < 64; o <<= 1) s += __shfl_xor(s, o);
    if (l == 0) rm[kk] = s * (1.f / 256.f);
  }
  __syncthreads();
  if (tid < 32) {
    float m = rm[tid];
    float mx = m;
#pragma unroll
    for (int o = 1; o < 32; o <<= 1) mx = fmaxf(mx, __shfl_xor(mx, o, 32));
    float e = __expf(m - mx);
    float sm = e;
#pragma unroll
    for (int o = 1; o < 32; o <<= 1) sm += __shfl_xor(sm, o, 32);
    wts[tid] = e / sm;
  }
  __syncthreads();
  float wsum = 0.f;
  for (int kk = 0; kk < 32; ++kk)
    wsum += enh[(size_t)(b * 32 + kk) * 256 + tid] * wts[kk];
  wgt[tid] = wsum;
  __syncthreads();
  const int co = tid;
  float yv = recb[co];
  for (int ci = 0; ci < 256; ++ci)
    yv += wgt[ci] * recT[ci * 256 + co];
  float s = bn2g[co] / sqrtf(bn2v[co] + EPSV);
  yfin[b * 256 + co] = yv * s + (bn2b[co] - bn2m[co] * s);
}

// ---------------------------------------------------------------------------
// out = x + yfin[b][c] broadcast
// ---------------------------------------------------------------------------
__global__ __launch_bounds__(256) void add_kernel(
    const float* __restrict__ x, const float* __restrict__ yfin,
    float* __restrict__ out)
{
  const size_t tot = (size_t)26214400 / 4;
  for (size_t idx = (size_t)blockIdx.x * 256 + threadIdx.x; idx < tot;
       idx += (size_t)gridDim.x * 256) {
    size_t e = idx * 4;
    int bc = (int)(e / 6400);
    f32x4 xv = ((const f32x4*)x)[idx];
    float a = yfin[bc];
    xv.x += a; xv.y += a; xv.z += a; xv.w += a;
    ((f32x4*)out)[idx] = xv;
  }
}

extern "C" void kernel_launch(void* const* d_in, const int* in_sizes, int n_in,
                              void* d_out, int out_size, void* d_ws, size_t ws_size,
                              hipStream_t stream)
{
  const float* x      = (const float*)d_in[0];
  const float* boxes  = (const float*)d_in[1];
  const float* conv_w = (const float*)d_in[2];
  const float* conv_b = (const float*)d_in[3];
  const float* bn1g   = (const float*)d_in[4];
  const float* bn1b   = (const float*)d_in[5];
  const float* bn1m   = (const float*)d_in[6];
  const float* bn1v   = (const float*)d_in[7];
  const float* wq     = (const float*)d_in[8];
  const float* bq     = (const float*)d_in[9];
  const float* wk     = (const float*)d_in[10];
  const float* bkp    = (const float*)d_in[11];
  const float* wv     = (const float*)d_in[12];
  const float* bv     = (const float*)d_in[13];
  const float* scale  = (const float*)d_in[14];
  const float* wo     = (const float*)d_in[15];
  const float* bo     = (const float*)d_in[16];
  const float* lng    = (const float*)d_in[17];
  const float* lnb    = (const float*)d_in[18];
  const float* rec_w  = (const float*)d_in[19];
  const float* rec_b  = (const float*)d_in[20];
  const float* bn2g   = (const float*)d_in[21];
  const float* bn2b   = (const float*)d_in[22];
  const float* bn2m   = (const float*)d_in[23];
  const float* bn2v   = (const float*)d_in[24];
  float* out = (float*)d_out;

  char* ws = (char*)d_ws;
  unsigned short* Wr   = (unsigned short*)(ws);                       // 1,179,648 B
  unsigned short* feat = (unsigned short*)(ws + 1179648);             // 52,428,800 B
  float* wT    = (float*)(ws + 53608448);                             // 1,310,720 B
  float* nodes = (float*)(ws + 54919168);
  float* qb    = nodes + 131072;
  float* kb    = qb + 131072;
  float* vb    = kb + 131072;
  float* enh   = vb + 131072;
  float* yfin  = enh + 131072;                                        // 16 KB
  float* zpad  = (float*)(ws + 57556992);                             // 1 KB zeros

  // xin (NHWC bf16, 52.4 MB) lives in d_out scratch — fully consumed by conv
  // before add_kernel overwrites d_out at the end. Deterministic each call.
  unsigned short* xin = (unsigned short*)d_out;

  hipLaunchKernelGGL(prep_convw_kernel, dim3(2304), dim3(256), 0, stream,
                     conv_w, Wr, zpad);
  hipLaunchKernelGGL(prep_transpose_kernel, dim3(1280), dim3(256), 0, stream,
                     wq, wk, wv, wo, rec_w, wT);
  hipLaunchKernelGGL(prep_nhwc_kernel, dim3(1280), dim3(256), 0, stream, x, xin);
  hipLaunchKernelGGL(conv_kernel, dim3(640), dim3(512), 0, stream,
                     xin, conv_b, bn1g, bn1b, bn1m, bn1v, Wr,
                     (const unsigned short*)zpad, feat);
  hipLaunchKernelGGL(roi_qkv_kernel, dim3(512), dim3(256), 0, stream,
                     feat, boxes, wT, bq, bkp, bv, nodes, qb, kb, vb);
  hipLaunchKernelGGL(attn_kernel, dim3(512), dim3(256), 0, stream,
                     qb, kb, vb, nodes, wT + 3 * 65536, bo, lng, lnb, scale, enh);
  hipLaunchKernelGGL(final_kernel, dim3(16), dim3(256), 0, stream,
                     enh, wT + 4 * 65536, rec_b, bn2g, bn2b, bn2m, bn2v, yfin);
  hipLaunchKernelGGL(add_kernel, dim3(2048), dim3(256), 0, stream, x, yfin, out);
}

// Round 5
// 269.572 us; speedup vs baseline: 1.7544x; 1.0798x over previous
//
#include <hip/hip_runtime.h>

#define EPSV 1e-5f

typedef __attribute__((ext_vector_type(8))) short short8v;
typedef __attribute__((ext_vector_type(4))) float f32x4;

static __device__ __forceinline__ unsigned short f2bf(float f) {
  unsigned int u = __float_as_uint(f);
  u += 0x7fff + ((u >> 16) & 1);
  return (unsigned short)(u >> 16);
}
static __device__ __forceinline__ float bf2f(unsigned short h) {
  return __uint_as_float(((unsigned int)h) << 16);
}

// async global->LDS 16B: dest = wave-uniform base + lane*16 (linear)
static __device__ __forceinline__ void glds16(const void* g, void* l) {
  __builtin_amdgcn_global_load_lds(
      (const __attribute__((address_space(1))) void*)g,
      (__attribute__((address_space(3))) void*)l, 16, 0, 0);
}

// ---------------------------------------------------------------------------
// Prep: conv weights -> Wr[t][cc][co][cil] bf16 (t = dy*3+dx, cc = ci/32)
// Also zeroes the 1KB zpad scratch (at xin+52428800B) used as OOB gl_lds src.
// ---------------------------------------------------------------------------
__global__ __launch_bounds__(256) void prep_convw_kernel(
    const float* __restrict__ cw, unsigned short* __restrict__ Wr,
    float* __restrict__ zpad)
{
  if (blockIdx.x == 0) zpad[threadIdx.x] = 0.f;
  int idx = blockIdx.x * 256 + threadIdx.x;
  if (idx >= 9 * 8 * 256 * 32) return;
  int cil = idx & 31;
  int rest = idx >> 5;
  int co = rest & 255;
  int tcc = rest >> 8;
  int cc = tcc & 7;
  int t = tcc >> 3;
  int dy = t / 3, dx = t - dy * 3;
  int ci = cc * 32 + cil;
  Wr[idx] = f2bf(cw[((co * 256 + ci) * 3 + dy) * 3 + dx]);
}

// Prep: transpose wq,wk,wv,wo,rec -> wT[m][ci][co] (f32)
__global__ __launch_bounds__(256) void prep_transpose_kernel(
    const float* __restrict__ wq, const float* __restrict__ wk,
    const float* __restrict__ wv, const float* __restrict__ wo,
    const float* __restrict__ rec, float* __restrict__ wT)
{
  int idx = blockIdx.x * 256 + threadIdx.x;
  if (idx >= 5 * 65536) return;
  int m = idx >> 16;
  int e = idx & 65535;
  int ci = e >> 8, co = e & 255;
  const float* src = (m == 0) ? wq : (m == 1) ? wk : (m == 2) ? wv : (m == 3) ? wo : rec;
  wT[idx] = src[co * 256 + ci];
}

// ---------------------------------------------------------------------------
// Prep: x NCHW f32 -> xin NHWC bf16 (LDS transpose per (b,y) row)
// ---------------------------------------------------------------------------
__global__ __launch_bounds__(256) void prep_nhwc_kernel(
    const float* __restrict__ x, unsigned short* __restrict__ xin)
{
  int blk = blockIdx.x;
  int b = blk / 80, y = blk - b * 80;
  __shared__ unsigned short t[80 * 257];
  const float* src = x + (size_t)b * 256 * 6400 + y * 80;
  for (int e = threadIdx.x; e < 80 * 256; e += 256) {
    int c = e / 80;
    int px = e - c * 80;
    t[px * 257 + c] = f2bf(src[(size_t)c * 6400 + px]);
  }
  __syncthreads();
  unsigned short* dst = xin + (size_t)blk * 80 * 256;
  for (int e = threadIdx.x; e < 80 * 32; e += 256) {
    int px = e >> 5;
    int c8 = e & 31;
    short8v v;
#pragma unroll
    for (int j = 0; j < 8; ++j) v[j] = t[px * 257 + c8 * 8 + j];
    *(short8v*)&dst[px * 256 + c8 * 8] = v;
  }
}

// ---------------------------------------------------------------------------
// Conv 3x3 + bias + BN + SiLU -> feat NHWC bf16.
// Block: 256 thr / 4 waves = 2(rows) x 2(co64). Tile M=160 px, N=128 co.
// 43.5 KB LDS + <=170 regs/wave -> 3 independent blocks/CU: one block's
// barrier drain overlaps the others' MFMA. W double-buffered via gl_lds per
// step; IN single-buffered, restaged at each cc boundary. XOR-swizzled.
// ---------------------------------------------------------------------------
__global__ __launch_bounds__(256, 3) void conv_kernel(
    const unsigned short* __restrict__ xin,   // zpad zeros at byte 52428800
    const float* __restrict__ convb,
    const float* __restrict__ bn1g, const float* __restrict__ bn1b,
    const float* __restrict__ bn1m, const float* __restrict__ bn1v,
    const unsigned short* __restrict__ Wr,
    unsigned short* __restrict__ feat)
{
  const int bid = blockIdx.x;
  const int orig = (bid & 7) * 160 + (bid >> 3);   // XCD-bijective (1280%8==0)
  const int b = orig / 80;
  const int rem = orig - b * 80;
  const int yb = (rem >> 1) * 2;
  const int coh = rem & 1;
  const int tid = threadIdx.x;
  const int w = tid >> 6, lane = tid & 63;
  const int bq = lane >> 4, r16 = lane & 15;
  const int wr = w >> 1, wc = w & 1;

  // IN @0: 1312 slots x 16B = 20992. W0 @21504, W1 @29696 (8KB each).
  // epilogue union [2][80][136] shorts = 43504.
  __shared__ __align__(16) char lds[43520];
  const int W0 = 21504, W1 = 29696;

  f32x4 acc[5][4];
#pragma unroll
  for (int i = 0; i < 5; ++i)
#pragma unroll
    for (int j = 0; j < 4; ++j)
      acc[i][j] = (f32x4){0.f, 0.f, 0.f, 0.f};

  const char* xinb = (const char*)xin;

  // IN staging byte offsets (cc=0), 6 parts (part 5: tid<32 only)
  unsigned ioff[6];
#pragma unroll
  for (int p = 0; p < 6; ++p) {
    int s = tid + (p << 8);
    int row4 = s / 328;
    int rm2 = s - row4 * 328;
    int px = rm2 >> 2;
    int qs = rm2 & 3;
    int chunk = qs ^ ((px >> 1) & 3);
    int gy = yb + row4 - 1, gx = px - 1;
    bool ok = (s < 1312) && ((unsigned)gy < 80u) && ((unsigned)gx < 80u);
    ioff[p] = ok ? (unsigned)(((((b * 80 + gy)) * 80 + gx) * 256 + chunk * 8) * 2)
                 : 52428800u;                 // zeros pad
  }

  // W staging byte offsets within a (t,cc) 16KB group, slots tid and tid+256
  const unsigned woffA =
      (unsigned)((((coh << 7) + (tid >> 2)) * 32 +
                  (((tid & 3) ^ ((tid >> 3) & 3)) * 8)) * 2);
  const int s2 = tid + 256;
  const unsigned woffB =
      (unsigned)((((coh << 7) + (s2 >> 2)) * 32 +
                  (((s2 & 3) ^ ((s2 >> 3) & 3)) * 8)) * 2);

  // swizzled read byte offsets
  int afo[3];
#pragma unroll
  for (int dx = 0; dx < 3; ++dx) {
    int u = r16 + dx;
    afo[dx] = u * 64 + ((bq ^ ((u >> 1) & 3)) << 4);
  }
  const int wfo = (wc * 64 + r16) * 64 + ((bq ^ ((r16 >> 1) & 3)) << 4);

  // prologue: stage IN(0) + W(step 0)
  {
#pragma unroll
    for (int p = 0; p < 5; ++p)
      glds16(xinb + ioff[p], lds + (((p << 8) + (w << 6)) << 4));
    if (tid < 32) glds16(xinb + ioff[5], lds + 20480);
    glds16((const char*)Wr + woffA, lds + W0 + ((w << 6) << 4));
    glds16((const char*)Wr + woffB, lds + W0 + 4096 + ((w << 6) << 4));
  }
  __syncthreads();

  for (int cc = 0; cc < 8; ++cc) {
#pragma unroll
    for (int t = 0; t < 9; ++t) {
      const int step = cc * 9 + t;
      const char* wb = lds + ((step & 1) ? W1 : W0);
      char* wbn = lds + ((step & 1) ? W0 : W1);
      if (step < 71) {
        const int nt = (t == 8) ? 0 : t + 1;
        const int ncc = (t == 8) ? cc + 1 : cc;
        const char* wg = (const char*)Wr + ((size_t)(nt * 8 + ncc) << 14);
        glds16(wg + woffA, wbn + ((w << 6) << 4));
        glds16(wg + woffB, wbn + 4096 + ((w << 6) << 4));
      }
      const int dy = (t * 11) >> 5;
      const int dx = t - dy * 3;
      short8v wf0 = *(const short8v*)(wb + wfo);
      short8v wf1 = *(const short8v*)(wb + wfo + 1024);
      short8v wf2 = *(const short8v*)(wb + wfo + 2048);
      short8v wf3 = *(const short8v*)(wb + wfo + 3072);
      const char* pa = lds + (wr + dy) * 5248 + afo[dx];
      short8v af0 = *(const short8v*)(pa);
      short8v af1 = *(const short8v*)(pa + 1024);
      short8v af2 = *(const short8v*)(pa + 2048);
      short8v af3 = *(const short8v*)(pa + 3072);
      short8v af4 = *(const short8v*)(pa + 4096);
      __builtin_amdgcn_s_setprio(1);
      acc[0][0] = __builtin_amdgcn_mfma_f32_16x16x32_bf16(af0, wf0, acc[0][0], 0, 0, 0);
      acc[0][1] = __builtin_amdgcn_mfma_f32_16x16x32_bf16(af0, wf1, acc[0][1], 0, 0, 0);
      acc[0][2] = __builtin_amdgcn_mfma_f32_16x16x32_bf16(af0, wf2, acc[0][2], 0, 0, 0);
      acc[0][3] = __builtin_amdgcn_mfma_f32_16x16x32_bf16(af0, wf3, acc[0][3], 0, 0, 0);
      acc[1][0] = __builtin_amdgcn_mfma_f32_16x16x32_bf16(af1, wf0, acc[1][0], 0, 0, 0);
      acc[1][1] = __builtin_amdgcn_mfma_f32_16x16x32_bf16(af1, wf1, acc[1][1], 0, 0, 0);
      acc[1][2] = __builtin_amdgcn_mfma_f32_16x16x32_bf16(af1, wf2, acc[1][2], 0, 0, 0);
      acc[1][3] = __builtin_amdgcn_mfma_f32_16x16x32_bf16(af1, wf3, acc[1][3], 0, 0, 0);
      acc[2][0] = __builtin_amdgcn_mfma_f32_16x16x32_bf16(af2, wf0, acc[2][0], 0, 0, 0);
      acc[2][1] = __builtin_amdgcn_mfma_f32_16x16x32_bf16(af2, wf1, acc[2][1], 0, 0, 0);
      acc[2][2] = __builtin_amdgcn_mfma_f32_16x16x32_bf16(af2, wf2, acc[2][2], 0, 0, 0);
      acc[2][3] = __builtin_amdgcn_mfma_f32_16x16x32_bf16(af2, wf3, acc[2][3], 0, 0, 0);
      acc[3][0] = __builtin_amdgcn_mfma_f32_16x16x32_bf16(af3, wf0, acc[3][0], 0, 0, 0);
      acc[3][1] = __builtin_amdgcn_mfma_f32_16x16x32_bf16(af3, wf1, acc[3][1], 0, 0, 0);
      acc[3][2] = __builtin_amdgcn_mfma_f32_16x16x32_bf16(af3, wf2, acc[3][2], 0, 0, 0);
      acc[3][3] = __builtin_amdgcn_mfma_f32_16x16x32_bf16(af3, wf3, acc[3][3], 0, 0, 0);
      acc[4][0] = __builtin_amdgcn_mfma_f32_16x16x32_bf16(af4, wf0, acc[4][0], 0, 0, 0);
      acc[4][1] = __builtin_amdgcn_mfma_f32_16x16x32_bf16(af4, wf1, acc[4][1], 0, 0, 0);
      acc[4][2] = __builtin_amdgcn_mfma_f32_16x16x32_bf16(af4, wf2, acc[4][2], 0, 0, 0);
      acc[4][3] = __builtin_amdgcn_mfma_f32_16x16x32_bf16(af4, wf3, acc[4][3], 0, 0, 0);
      __builtin_amdgcn_s_setprio(0);
      if (t == 8) {
        __syncthreads();                       // all reads of IN(cc) done
        if (cc < 7) {
          const char* sadv = xinb + ((cc + 1) << 6);
#pragma unroll
          for (int p = 0; p < 5; ++p)
            glds16(sadv + ioff[p], lds + (((p << 8) + (w << 6)) << 4));
          if (tid < 32) glds16(sadv + ioff[5], lds + 20480);
        }
      }
      __syncthreads();                         // drain W(+IN) prefetch
    }
  }

  // epilogue: bias + BN + SiLU -> ep[2][80][136] -> coalesced NHWC
  unsigned short* ep = (unsigned short*)lds;
#pragma unroll
  for (int cf = 0; cf < 4; ++cf) {
    int col = wc * 64 + cf * 16 + r16;        // within 128
    int cog = (coh << 7) + col;
    float s  = bn1g[cog] / sqrtf(bn1v[cog] + EPSV);
    float sh = bn1b[cog] - bn1m[cog] * s;
    float cb = convb[cog];
#pragma unroll
    for (int xf = 0; xf < 5; ++xf) {
#pragma unroll
      for (int rg = 0; rg < 4; ++rg) {
        int px = xf * 16 + bq * 4 + rg;       // D row = 4*(lane>>4)+reg (m89)
        float v = (acc[xf][cf][rg] + cb) * s + sh;
        v = v / (1.f + __expf(-v));           // SiLU
        ep[(wr * 80 + px) * 136 + col] = f2bf(v);
      }
    }
  }
  __syncthreads();
  unsigned short* fout = feat + ((size_t)((b * 80 + yb) * 80)) * 256 + (coh << 7);
  for (int i2 = tid; i2 < 2560; i2 += 256) {
    int row = i2 / 1280;
    int rm3 = i2 - row * 1280;
    int px = rm3 >> 4;
    int c16 = rm3 & 15;
    *(short8v*)&fout[(row * 80 + px) * 256 + (c16 << 3)] =
        *(const short8v*)&ep[(row * 80 + px) * 136 + (c16 << 3)];
  }
}

// ---------------------------------------------------------------------------
// Fused roi_align (1x1, S=4) + q,k,v projections. Block per node.
// ---------------------------------------------------------------------------
__global__ __launch_bounds__(256) void roi_qkv_kernel(
    const unsigned short* __restrict__ feat,
    const float* __restrict__ boxes, const float* __restrict__ wT,
    const float* __restrict__ bq, const float* __restrict__ bk,
    const float* __restrict__ bv,
    float* __restrict__ nodes, float* __restrict__ q,
    float* __restrict__ k, float* __restrict__ v)
{
  const int n = blockIdx.x;
  const int b = n >> 5;
  const int c = threadIdx.x;
  __shared__ float nd[256];
  const float* bx = boxes + n * 4;
  float x1 = bx[0] * 79.f, y1 = bx[1] * 79.f, x2 = bx[2] * 79.f, y2 = bx[3] * 79.f;
  float rw = fmaxf(x2 - x1, 1.f), rh = fmaxf(y2 - y1, 1.f);
  const unsigned short* fb = feat + (size_t)b * 80 * 80 * 256;
  float acc = 0.f;
#pragma unroll
  for (int sy = 0; sy < 4; ++sy) {
    float yy = y1 + (sy + 0.5f) * 0.25f * rh;
#pragma unroll
    for (int sx = 0; sx < 4; ++sx) {
      float xx = x1 + (sx + 0.5f) * 0.25f * rw;
      if (yy < -1.f || yy > 80.f || xx < -1.f || xx > 80.f) continue;
      float yc = fminf(fmaxf(yy, 0.f), 79.f);
      float xc = fminf(fmaxf(xx, 0.f), 79.f);
      float y0 = floorf(yc), x0f = floorf(xc);
      int y0i = (int)y0, x0i = (int)x0f;
      int y1i = min(y0i + 1, 79), x1i = min(x0i + 1, 79);
      float ly = yc - y0, lx = xc - x0f;
      float hy = 1.f - ly, hx = 1.f - lx;
      float v00 = bf2f(fb[((y0i * 80) + x0i) * 256 + c]);
      float v01 = bf2f(fb[((y0i * 80) + x1i) * 256 + c]);
      float v10 = bf2f(fb[((y1i * 80) + x0i) * 256 + c]);
      float v11 = bf2f(fb[((y1i * 80) + x1i) * 256 + c]);
      acc += hy * hx * v00 + hy * lx * v01 + ly * hx * v10 + ly * lx * v11;
    }
  }
  float val = acc * 0.0625f;
  nodes[n * 256 + c] = val;
  nd[c] = val;
  __syncthreads();
  float aq = 0.f, ak = 0.f, av = 0.f;
  const float* wqT = wT;
  const float* wkT = wT + 65536;
  const float* wvT = wT + 131072;
#pragma unroll 4
  for (int ci = 0; ci < 256; ++ci) {
    float nv = nd[ci];
    aq += nv * wqT[ci * 256 + c];
    ak += nv * wkT[ci * 256 + c];
    av += nv * wvT[ci * 256 + c];
  }
  q[n * 256 + c] = aq + bq[c];
  k[n * 256 + c] = ak + bk[c];
  v[n * 256 + c] = av + bv[c];
}

// ---------------------------------------------------------------------------
// Attention over all 512 nodes + out-proj + residual + LayerNorm.
// Block per query node i.
// ---------------------------------------------------------------------------
__global__ __launch_bounds__(256) void attn_kernel(
    const float* __restrict__ q, const float* __restrict__ k,
    const float* __restrict__ v, const float* __restrict__ nodes,
    const float* __restrict__ woT, const float* __restrict__ bo,
    const float* __restrict__ lng, const float* __restrict__ lnb,
    const float* __restrict__ scale_p, float* __restrict__ enh)
{
  const int i = blockIdx.x;
  const int tid = threadIdx.x;
  const float scale = scale_p[0];
  __shared__ __align__(16) float qs[256];
  __shared__ float sc[512 * 8];
  __shared__ float msgs[256];
  __shared__ float r1[4], r2[4];
  qs[tid] = q[i * 256 + tid];
  __syncthreads();
  {
    const int h = tid & 7, jl = tid >> 3;
    for (int jc = 0; jc < 16; ++jc) {
      int j = jc * 32 + jl;
      const f32x4* kr = (const f32x4*)(k + (size_t)j * 256 + h * 32);
      const f32x4* qr = (const f32x4*)(qs + h * 32);
      float s = 0.f;
#pragma unroll
      for (int d4 = 0; d4 < 8; ++d4) {
        f32x4 kv = kr[d4], qv = qr[d4];
        s += kv.x * qv.x + kv.y * qv.y + kv.z * qv.z + kv.w * qv.w;
      }
      sc[j * 8 + h] = s * scale;
    }
  }
  __syncthreads();
  const int hh = tid >> 5, l32 = tid & 31;
  float mx = -1e30f;
  for (int j = l32; j < 512; j += 32) mx = fmaxf(mx, sc[j * 8 + hh]);
#pragma unroll
  for (int o = 1; o < 32; o <<= 1) mx = fmaxf(mx, __shfl_xor(mx, o, 32));
  float sum = 0.f;
  for (int j = l32; j < 512; j += 32) {
    float e = __expf(sc[j * 8 + hh] - mx);
    sc[j * 8 + hh] = e;
    sum += e;
  }
#pragma unroll
  for (int o = 1; o < 32; o <<= 1) sum += __shfl_xor(sum, o, 32);
  float inv = 1.f / sum;
  __syncthreads();
  {
    const int d = l32;
    float m = 0.f;
    for (int j = 0; j < 512; ++j)
      m += sc[j * 8 + hh] * v[(size_t)j * 256 + hh * 32 + d];
    msgs[hh * 32 + d] = m * inv;
  }
  __syncthreads();
  const int co = tid;
  float yv = nodes[i * 256 + co] + bo[co];
  for (int ci = 0; ci < 256; ++ci)
    yv += msgs[ci] * woT[ci * 256 + co];
  float s1 = yv, s2 = yv * yv;
#pragma unroll
  for (int o = 1; o < 64; o <<= 1) { s1 += __shfl_xor(s1, o); s2 += __shfl_xor(s2, o); }
  if ((tid & 63) == 0) { r1[tid >> 6] = s1; r2[tid >> 6] = s2; }
  __syncthreads();
  float S1 = r1[0] + r1[1] + r1[2] + r1[3];
  float S2 = r2[0] + r2[1] + r2[2] + r2[3];
  float mu = S1 * (1.f / 256.f);
  float var = S2 * (1.f / 256.f) - mu * mu;
  float nrm = (yv - mu) * rsqrtf(var + EPSV);
  enh[i * 256 + co] = nrm * lng[co] + lnb[co];
}

// ---------------------------------------------------------------------------
// Per-batch pooling + rec 1x1 conv + BN2 -> yfin[b][c]. Block per batch.
// ---------------------------------------------------------------------------
__global__ __launch_bounds__(256) void final_kernel(
    const float* __restrict__ enh, const float* __restrict__ recT,
    const float* __restrict__ recb,
    const float* __restrict__ bn2g, const float* __restrict__ bn2b,
    const float* __restrict__ bn2m, const float* __restrict__ bn2v,
    float* __restrict__ yfin)
{
  const int b = blockIdx.x;
  const int tid = threadIdx.x;
  const int wv = tid >> 6, l = tid & 63;
  __shared__ float rm[32], wts[32], wgt[256];
  for (int kk = wv; kk < 32; kk += 4) {
    const float* er = enh + (size_t)(b * 32 + kk) * 256;
    float s = er[l] + er[l + 64] + er[l + 128] + er[l + 192];
#pragma unroll
    for (int o = 1; o < 64; o <<= 1) s += __shfl_xor(s, o);
    if (l == 0) rm[kk] = s * (1.f / 256.f);
  }
  __syncthreads();
  if (tid < 32) {
    float m = rm[tid];
    float mx = m;
#pragma unroll
    for (int o = 1; o < 32; o <<= 1) mx = fmaxf(mx, __shfl_xor(mx, o, 32));
    float e = __expf(m - mx);
    float sm = e;
#pragma unroll
    for (int o = 1; o < 32; o <<= 1) sm += __shfl_xor(sm, o, 32);
    wts[tid] = e / sm;
  }
  __syncthreads();
  float wsum = 0.f;
  for (int kk = 0; kk < 32; ++kk)
    wsum += enh[(size_t)(b * 32 + kk) * 256 + tid] * wts[kk];
  wgt[tid] = wsum;
  __syncthreads();
  const int co = tid;
  float yv = recb[co];
  for (int ci = 0; ci < 256; ++ci)
    yv += wgt[ci] * recT[ci * 256 + co];
  float s = bn2g[co] / sqrtf(bn2v[co] + EPSV);
  yfin[b * 256 + co] = yv * s + (bn2b[co] - bn2m[co] * s);
}

// ---------------------------------------------------------------------------
// out = x + yfin[b][c] broadcast
// ---------------------------------------------------------------------------
__global__ __launch_bounds__(256) void add_kernel(
    const float* __restrict__ x, const float* __restrict__ yfin,
    float* __restrict__ out)
{
  const size_t tot = (size_t)26214400 / 4;
  for (size_t idx = (size_t)blockIdx.x * 256 + threadIdx.x; idx < tot;
       idx += (size_t)gridDim.x * 256) {
    size_t e = idx * 4;
    int bc = (int)(e / 6400);
    f32x4 xv = ((const f32x4*)x)[idx];
    float a = yfin[bc];
    xv.x += a; xv.y += a; xv.z += a; xv.w += a;
    ((f32x4*)out)[idx] = xv;
  }
}

extern "C" void kernel_launch(void* const* d_in, const int* in_sizes, int n_in,
                              void* d_out, int out_size, void* d_ws, size_t ws_size,
                              hipStream_t stream)
{
  const float* x      = (const float*)d_in[0];
  const float* boxes  = (const float*)d_in[1];
  const float* conv_w = (const float*)d_in[2];
  const float* conv_b = (const float*)d_in[3];
  const float* bn1g   = (const float*)d_in[4];
  const float* bn1b   = (const float*)d_in[5];
  const float* bn1m   = (const float*)d_in[6];
  const float* bn1v   = (const float*)d_in[7];
  const float* wq     = (const float*)d_in[8];
  const float* bq     = (const float*)d_in[9];
  const float* wk     = (const float*)d_in[10];
  const float* bkp    = (const float*)d_in[11];
  const float* wv     = (const float*)d_in[12];
  const float* bv     = (const float*)d_in[13];
  const float* scale  = (const float*)d_in[14];
  const float* wo     = (const float*)d_in[15];
  const float* bo     = (const float*)d_in[16];
  const float* lng    = (const float*)d_in[17];
  const float* lnb    = (const float*)d_in[18];
  const float* rec_w  = (const float*)d_in[19];
  const float* rec_b  = (const float*)d_in[20];
  const float* bn2g   = (const float*)d_in[21];
  const float* bn2b   = (const float*)d_in[22];
  const float* bn2m   = (const float*)d_in[23];
  const float* bn2v   = (const float*)d_in[24];
  float* out = (float*)d_out;

  char* ws = (char*)d_ws;
  unsigned short* Wr   = (unsigned short*)(ws);                       // 1,179,648 B
  unsigned short* feat = (unsigned short*)(ws + 1179648);             // 52,428,800 B
  float* wT    = (float*)(ws + 53608448);                             // 1,310,720 B
  float* nodes = (float*)(ws + 54919168);
  float* qb    = nodes + 131072;
  float* kb    = qb + 131072;
  float* vb    = kb + 131072;
  float* enh   = vb + 131072;
  float* yfin  = enh + 131072;                                        // 16 KB

  // xin (NHWC bf16, 52.4 MB) + 1KB zero pad live in d_out scratch — fully
  // consumed by conv before add_kernel overwrites d_out. Deterministic: the
  // pad is re-zeroed by prep_convw every call.
  unsigned short* xin = (unsigned short*)d_out;
  float* zpad = (float*)((char*)d_out + 52428800);

  hipLaunchKernelGGL(prep_convw_kernel, dim3(2304), dim3(256), 0, stream,
                     conv_w, Wr, zpad);
  hipLaunchKernelGGL(prep_transpose_kernel, dim3(1280), dim3(256), 0, stream,
                     wq, wk, wv, wo, rec_w, wT);
  hipLaunchKernelGGL(prep_nhwc_kernel, dim3(1280), dim3(256), 0, stream, x, xin);
  hipLaunchKernelGGL(conv_kernel, dim3(1280), dim3(256), 0, stream,
                     xin, conv_b, bn1g, bn1b, bn1m, bn1v, Wr, feat);
  hipLaunchKernelGGL(roi_qkv_kernel, dim3(512), dim3(256), 0, stream,
                     feat, boxes, wT, bq, bkp, bv, nodes, qb, kb, vb);
  hipLaunchKernelGGL(attn_kernel, dim3(512), dim3(256), 0, stream,
                     qb, kb, vb, nodes, wT + 3 * 65536, bo, lng, lnb, scale, enh);
  hipLaunchKernelGGL(final_kernel, dim3(16), dim3(256), 0, stream,
                     enh, wT + 4 * 65536, rec_b, bn2g, bn2b, bn2m, bn2v, yfin);
  hipLaunchKernelGGL(add_kernel, dim3(2048), dim3(256), 0, stream, x, yfin, out);
}

// Round 6
// 207.997 us; speedup vs baseline: 2.2738x; 1.2960x over previous
//
#include <hip/hip_runtime.h>

#define EPSV 1e-5f

typedef __attribute__((ext_vector_type(8))) short short8v;
typedef __attribute__((ext_vector_type(4))) float f32x4;

static __device__ __forceinline__ unsigned short f2bf(float f) {
  unsigned int u = __float_as_uint(f);
  u += 0x7fff + ((u >> 16) & 1);
  return (unsigned short)(u >> 16);
}
static __device__ __forceinline__ float bf2f(unsigned short h) {
  return __uint_as_float(((unsigned int)h) << 16);
}

// async global->LDS 16B: dest = wave-uniform base + lane*16 (linear)
static __device__ __forceinline__ void glds16(const void* g, void* l) {
  __builtin_amdgcn_global_load_lds(
      (const __attribute__((address_space(1))) void*)g,
      (__attribute__((address_space(3))) void*)l, 16, 0, 0);
}

// ---------------------------------------------------------------------------
// Prep: conv weights -> Wr[t][cc][co][cil] bf16 (t = dy*3+dx, cc = ci/32)
// Also zeroes the 1KB zpad scratch (at xin+52428800B) used as OOB gl_lds src.
// ---------------------------------------------------------------------------
__global__ __launch_bounds__(256) void prep_convw_kernel(
    const float* __restrict__ cw, unsigned short* __restrict__ Wr,
    float* __restrict__ zpad)
{
  if (blockIdx.x == 0) zpad[threadIdx.x] = 0.f;
  int idx = blockIdx.x * 256 + threadIdx.x;
  if (idx >= 9 * 8 * 256 * 32) return;
  int cil = idx & 31;
  int rest = idx >> 5;
  int co = rest & 255;
  int tcc = rest >> 8;
  int cc = tcc & 7;
  int t = tcc >> 3;
  int dy = t / 3, dx = t - dy * 3;
  int ci = cc * 32 + cil;
  Wr[idx] = f2bf(cw[((co * 256 + ci) * 3 + dy) * 3 + dx]);
}

// Prep: transpose wq,wk,wv,wo,rec -> wT[m][ci][co] (f32)
__global__ __launch_bounds__(256) void prep_transpose_kernel(
    const float* __restrict__ wq, const float* __restrict__ wk,
    const float* __restrict__ wv, const float* __restrict__ wo,
    const float* __restrict__ rec, float* __restrict__ wT)
{
  int idx = blockIdx.x * 256 + threadIdx.x;
  if (idx >= 5 * 65536) return;
  int m = idx >> 16;
  int e = idx & 65535;
  int ci = e >> 8, co = e & 255;
  const float* src = (m == 0) ? wq : (m == 1) ? wk : (m == 2) ? wv : (m == 3) ? wo : rec;
  wT[idx] = src[co * 256 + ci];
}

// ---------------------------------------------------------------------------
// Prep: x NCHW f32 -> xin NHWC bf16 (LDS transpose per (b,y) row), f32x4 reads
// ---------------------------------------------------------------------------
__global__ __launch_bounds__(256) void prep_nhwc_kernel(
    const float* __restrict__ x, unsigned short* __restrict__ xin)
{
  int blk = blockIdx.x;
  int b = blk / 80, y = blk - b * 80;
  __shared__ unsigned short t[80 * 257];
  const float* src = x + (size_t)b * 256 * 6400 + y * 80;
  for (int e = threadIdx.x; e < 256 * 20; e += 256) {
    int c = e / 20;
    int px4 = e - c * 20;
    f32x4 v = *(const f32x4*)&src[(size_t)c * 6400 + px4 * 4];
#pragma unroll
    for (int j = 0; j < 4; ++j)
      t[(px4 * 4 + j) * 257 + c] = f2bf(v[j]);
  }
  __syncthreads();
  unsigned short* dst = xin + (size_t)blk * 80 * 256;
  for (int e = threadIdx.x; e < 80 * 32; e += 256) {
    int px = e >> 5;
    int c8 = e & 31;
    short8v v;
#pragma unroll
    for (int j = 0; j < 8; ++j) v[j] = t[px * 257 + c8 * 8 + j];
    *(short8v*)&dst[px * 256 + c8 * 8] = v;
  }
}

// ---------------------------------------------------------------------------
// Fused direct conv@roi-pixels + BN + SiLU + bilinear avg -> nodes[512][256].
// Block per node: M = 64 corner pixels (16 samples x 4), N = 256 co,
// K = 9 taps x 256 ci. 4 waves each own a co-64 slice; acc[4][4] (64 AGPR).
// Per step (t,cc): stage IN 4KB (gathered, per-lane src) + W 16KB via gl_lds,
// double-buffered, one barrier per step, 16 MFMA/wave. Swizzle = R5's.
// Skips the 52MB feat buffer entirely (conv computed only where sampled).
// ---------------------------------------------------------------------------
__global__ __launch_bounds__(256, 2) void roiconv_kernel(
    const unsigned short* __restrict__ xin,   // zpad zeros at byte 52428800
    const float* __restrict__ boxes,
    const float* __restrict__ convb,
    const float* __restrict__ bn1g, const float* __restrict__ bn1b,
    const float* __restrict__ bn1m, const float* __restrict__ bn1v,
    const unsigned short* __restrict__ Wr,
    float* __restrict__ nodes)
{
  const int bid = blockIdx.x;
  const int n = (bid & 7) * 64 + (bid >> 3);   // XCD-bijective (512%8==0)
  const int b = n >> 5;
  const int tid = threadIdx.x;
  const int w = tid >> 6, lane = tid & 63;
  const int bq = lane >> 4, r16 = lane & 15;

  // IN0@0 IN1@4096 (4KB each), W0@8192 W1@24576 (16KB each);
  // epilogue union: epf[64][256] f32 = 65536; wcoef @65536 (256B)
  __shared__ __align__(16) char lds[65792];
  float* wcoef = (float*)(lds + 65536);
  const int IN0 = 0, IN1 = 4096, W0 = 8192, W1 = 24576;

  // ---- geometry for this thread's pixel px = tid>>2 ----
  const int px = tid >> 2;
  const float* bx = boxes + n * 4;
  float x1 = bx[0] * 79.f, y1 = bx[1] * 79.f, x2 = bx[2] * 79.f, y2 = bx[3] * 79.f;
  float rwd = fmaxf(x2 - x1, 1.f), rh = fmaxf(y2 - y1, 1.f);
  int s = px >> 2;
  int sy = s >> 2, sx = s & 3;
  float yy = y1 + (sy + 0.5f) * 0.25f * rh;
  float xx = x1 + (sx + 0.5f) * 0.25f * rwd;
  bool valid = (yy >= -1.f) && (yy <= 80.f) && (xx >= -1.f) && (xx <= 80.f);
  float yc = fminf(fmaxf(yy, 0.f), 79.f), xc = fminf(fmaxf(xx, 0.f), 79.f);
  float y0f = floorf(yc), x0f = floorf(xc);
  int y0i = (int)y0f, x0i = (int)x0f;
  int y1i = min(y0i + 1, 79), x1i = min(x0i + 1, 79);
  float ly = yc - y0f, lx = xc - x0f, hy = 1.f - ly, hx = 1.f - lx;
  int py = (px & 2) ? y1i : y0i;
  int pxx = (px & 1) ? x1i : x0i;
  if ((tid & 3) == 0)
    wcoef[px] = ((px & 2) ? ly : hy) * ((px & 1) ? lx : hx) *
                (valid ? 0.0625f : 0.f);

  // ---- staging source offsets (R5-verified swizzle pattern) ----
  const int chunk = (tid & 3) ^ ((px >> 1) & 3);
  unsigned ioff[9];
#pragma unroll
  for (int t = 0; t < 9; ++t) {
    int dy = t / 3, dx = t - dy * 3;
    int cy = py + dy - 1, cx = pxx + dx - 1;
    bool ok = ((unsigned)cy < 80u) && ((unsigned)cx < 80u);
    ioff[t] = ok ? (unsigned)((((b * 80 + cy) * 80 + cx) * 256 + chunk * 8) * 2)
                 : 52428800u;
  }
  unsigned woff[4];
#pragma unroll
  for (int i = 0; i < 4; ++i) {
    int s2 = tid + (i << 8);
    int wco = s2 >> 2;
    int wch = (s2 & 3) ^ ((wco >> 1) & 3);
    woff[i] = (unsigned)((wco * 32 + wch * 8) * 2);
  }
  const int laneoff = r16 * 64 + ((bq ^ ((r16 >> 1) & 3)) << 4);
  const char* xinb = (const char*)xin;
  const char* Wrb = (const char*)Wr;

  f32x4 acc[4][4];
#pragma unroll
  for (int i = 0; i < 4; ++i)
#pragma unroll
    for (int j = 0; j < 4; ++j)
      acc[i][j] = (f32x4){0.f, 0.f, 0.f, 0.f};

  // prologue: stage step 0 (t=0, cc=0)
  glds16(xinb + ioff[0], lds + IN0 + ((w << 6) << 4));
#pragma unroll
  for (int i = 0; i < 4; ++i)
    glds16(Wrb + woff[i], lds + W0 + (((i << 8) + (w << 6)) << 4));
  __syncthreads();

  for (int cc = 0; cc < 8; ++cc) {
#pragma unroll
    for (int t = 0; t < 9; ++t) {
      const int step = cc * 9 + t;
      const char* inb = lds + ((step & 1) ? IN1 : IN0);
      const char* wb  = lds + ((step & 1) ? W1 : W0);
      char* innx = lds + ((step & 1) ? IN0 : IN1);
      char* wbn  = lds + ((step & 1) ? W0 : W1);
      if (step < 71) {
        const int nt = (t == 8) ? 0 : t + 1;
        const int ncc = (t == 8) ? cc + 1 : cc;
        glds16(xinb + ioff[nt] + ncc * 64, innx + ((w << 6) << 4));
        const char* wg = Wrb + ((size_t)(nt * 8 + ncc) << 14);
#pragma unroll
        for (int i = 0; i < 4; ++i)
          glds16(wg + woff[i], wbn + (((i << 8) + (w << 6)) << 4));
      }
      const char* pa = inb + laneoff;
      const char* pw = wb + w * 4096 + laneoff;
      short8v af0 = *(const short8v*)(pa);
      short8v af1 = *(const short8v*)(pa + 1024);
      short8v af2 = *(const short8v*)(pa + 2048);
      short8v af3 = *(const short8v*)(pa + 3072);
      short8v wf0 = *(const short8v*)(pw);
      short8v wf1 = *(const short8v*)(pw + 1024);
      short8v wf2 = *(const short8v*)(pw + 2048);
      short8v wf3 = *(const short8v*)(pw + 3072);
      __builtin_amdgcn_s_setprio(1);
      acc[0][0] = __builtin_amdgcn_mfma_f32_16x16x32_bf16(af0, wf0, acc[0][0], 0, 0, 0);
      acc[0][1] = __builtin_amdgcn_mfma_f32_16x16x32_bf16(af0, wf1, acc[0][1], 0, 0, 0);
      acc[0][2] = __builtin_amdgcn_mfma_f32_16x16x32_bf16(af0, wf2, acc[0][2], 0, 0, 0);
      acc[0][3] = __builtin_amdgcn_mfma_f32_16x16x32_bf16(af0, wf3, acc[0][3], 0, 0, 0);
      acc[1][0] = __builtin_amdgcn_mfma_f32_16x16x32_bf16(af1, wf0, acc[1][0], 0, 0, 0);
      acc[1][1] = __builtin_amdgcn_mfma_f32_16x16x32_bf16(af1, wf1, acc[1][1], 0, 0, 0);
      acc[1][2] = __builtin_amdgcn_mfma_f32_16x16x32_bf16(af1, wf2, acc[1][2], 0, 0, 0);
      acc[1][3] = __builtin_amdgcn_mfma_f32_16x16x32_bf16(af1, wf3, acc[1][3], 0, 0, 0);
      acc[2][0] = __builtin_amdgcn_mfma_f32_16x16x32_bf16(af2, wf0, acc[2][0], 0, 0, 0);
      acc[2][1] = __builtin_amdgcn_mfma_f32_16x16x32_bf16(af2, wf1, acc[2][1], 0, 0, 0);
      acc[2][2] = __builtin_amdgcn_mfma_f32_16x16x32_bf16(af2, wf2, acc[2][2], 0, 0, 0);
      acc[2][3] = __builtin_amdgcn_mfma_f32_16x16x32_bf16(af2, wf3, acc[2][3], 0, 0, 0);
      acc[3][0] = __builtin_amdgcn_mfma_f32_16x16x32_bf16(af3, wf0, acc[3][0], 0, 0, 0);
      acc[3][1] = __builtin_amdgcn_mfma_f32_16x16x32_bf16(af3, wf1, acc[3][1], 0, 0, 0);
      acc[3][2] = __builtin_amdgcn_mfma_f32_16x16x32_bf16(af3, wf2, acc[3][2], 0, 0, 0);
      acc[3][3] = __builtin_amdgcn_mfma_f32_16x16x32_bf16(af3, wf3, acc[3][3], 0, 0, 0);
      __builtin_amdgcn_s_setprio(0);
      __syncthreads();
    }
  }

  // epilogue: bias+BN+SiLU (f32) -> epf[px][co]; then bilinear combine
  float* epf = (float*)lds;
#pragma unroll
  for (int cf = 0; cf < 4; ++cf) {
    int co = w * 64 + cf * 16 + r16;
    float sc = bn1g[co] / sqrtf(bn1v[co] + EPSV);
    float sh = bn1b[co] - bn1m[co] * sc;
    float cb = convb[co];
#pragma unroll
    for (int mf = 0; mf < 4; ++mf) {
#pragma unroll
      for (int rg = 0; rg < 4; ++rg) {
        int pxo = mf * 16 + bq * 4 + rg;    // D row = 4*(lane>>4)+reg (m89)
        float v = (acc[mf][cf][rg] + cb) * sc + sh;
        v = v / (1.f + __expf(-v));         // SiLU
        epf[pxo * 256 + co] = v;
      }
    }
  }
  __syncthreads();
  const int c = tid;
  float val = 0.f;
#pragma unroll
  for (int p = 0; p < 64; ++p)
    val += wcoef[p] * epf[p * 256 + c];
  nodes[n * 256 + c] = val;
}

// ---------------------------------------------------------------------------
// q,k,v projections. Block handles 8 nodes; thread = output channel.
// ---------------------------------------------------------------------------
__global__ __launch_bounds__(256) void qkv_kernel(
    const float* __restrict__ nodes, const float* __restrict__ wT,
    const float* __restrict__ bq, const float* __restrict__ bk,
    const float* __restrict__ bv,
    float* __restrict__ q, float* __restrict__ k, float* __restrict__ v)
{
  const int blk = blockIdx.x;
  const int co = threadIdx.x;
  __shared__ float nd[8][256];
  for (int i = threadIdx.x; i < 2048; i += 256)
    nd[i >> 8][i & 255] = nodes[blk * 2048 + i];
  __syncthreads();
  float aq[8] = {0,0,0,0,0,0,0,0};
  float ak[8] = {0,0,0,0,0,0,0,0};
  float av[8] = {0,0,0,0,0,0,0,0};
  const float* wqT = wT;
  const float* wkT = wT + 65536;
  const float* wvT = wT + 131072;
  for (int ci = 0; ci < 256; ++ci) {
    float wq_ = wqT[ci * 256 + co];
    float wk_ = wkT[ci * 256 + co];
    float wv_ = wvT[ci * 256 + co];
#pragma unroll
    for (int r = 0; r < 8; ++r) {
      float nv = nd[r][ci];
      aq[r] += nv * wq_;
      ak[r] += nv * wk_;
      av[r] += nv * wv_;
    }
  }
  float bq_ = bq[co], bk_ = bk[co], bv_ = bv[co];
#pragma unroll
  for (int r = 0; r < 8; ++r) {
    int n = blk * 8 + r;
    q[n * 256 + co] = aq[r] + bq_;
    k[n * 256 + co] = ak[r] + bk_;
    v[n * 256 + co] = av[r] + bv_;
  }
}

// ---------------------------------------------------------------------------
// Attention over all 512 nodes + out-proj + residual + LayerNorm.
// Block per query node i.
// ---------------------------------------------------------------------------
__global__ __launch_bounds__(256) void attn_kernel(
    const float* __restrict__ q, const float* __restrict__ k,
    const float* __restrict__ v, const float* __restrict__ nodes,
    const float* __restrict__ woT, const float* __restrict__ bo,
    const float* __restrict__ lng, const float* __restrict__ lnb,
    const float* __restrict__ scale_p, float* __restrict__ enh)
{
  const int i = blockIdx.x;
  const int tid = threadIdx.x;
  const float scale = scale_p[0];
  __shared__ __align__(16) float qs[256];
  __shared__ float sc[512 * 8];
  __shared__ float msgs[256];
  __shared__ float r1[4], r2[4];
  qs[tid] = q[i * 256 + tid];
  __syncthreads();
  {
    const int h = tid & 7, jl = tid >> 3;
    for (int jc = 0; jc < 16; ++jc) {
      int j = jc * 32 + jl;
      const f32x4* kr = (const f32x4*)(k + (size_t)j * 256 + h * 32);
      const f32x4* qr = (const f32x4*)(qs + h * 32);
      float s = 0.f;
#pragma unroll
      for (int d4 = 0; d4 < 8; ++d4) {
        f32x4 kv = kr[d4], qv = qr[d4];
        s += kv.x * qv.x + kv.y * qv.y + kv.z * qv.z + kv.w * qv.w;
      }
      sc[j * 8 + h] = s * scale;
    }
  }
  __syncthreads();
  const int hh = tid >> 5, l32 = tid & 31;
  float mx = -1e30f;
  for (int j = l32; j < 512; j += 32) mx = fmaxf(mx, sc[j * 8 + hh]);
#pragma unroll
  for (int o = 1; o < 32; o <<= 1) mx = fmaxf(mx, __shfl_xor(mx, o, 32));
  float sum = 0.f;
  for (int j = l32; j < 512; j += 32) {
    float e = __expf(sc[j * 8 + hh] - mx);
    sc[j * 8 + hh] = e;
    sum += e;
  }
#pragma unroll
  for (int o = 1; o < 32; o <<= 1) sum += __shfl_xor(sum, o, 32);
  float inv = 1.f / sum;
  __syncthreads();
  {
    const int d = l32;
    float m = 0.f;
    for (int j = 0; j < 512; ++j)
      m += sc[j * 8 + hh] * v[(size_t)j * 256 + hh * 32 + d];
    msgs[hh * 32 + d] = m * inv;
  }
  __syncthreads();
  const int co = tid;
  float yv = nodes[i * 256 + co] + bo[co];
  for (int ci = 0; ci < 256; ++ci)
    yv += msgs[ci] * woT[ci * 256 + co];
  float s1 = yv, s2 = yv * yv;
#pragma unroll
  for (int o = 1; o < 64; o <<= 1) { s1 += __shfl_xor(s1, o); s2 += __shfl_xor(s2, o); }
  if ((tid & 63) == 0) { r1[tid >> 6] = s1; r2[tid >> 6] = s2; }
  __syncthreads();
  float S1 = r1[0] + r1[1] + r1[2] + r1[3];
  float S2 = r2[0] + r2[1] + r2[2] + r2[3];
  float mu = S1 * (1.f / 256.f);
  float var = S2 * (1.f / 256.f) - mu * mu;
  float nrm = (yv - mu) * rsqrtf(var + EPSV);
  enh[i * 256 + co] = nrm * lng[co] + lnb[co];
}

// ---------------------------------------------------------------------------
// Per-batch pooling + rec 1x1 conv + BN2 -> yfin[b][c]. Block per batch.
// ---------------------------------------------------------------------------
__global__ __launch_bounds__(256) void final_kernel(
    const float* __restrict__ enh, const float* __restrict__ recT,
    const float* __restrict__ recb,
    const float* __restrict__ bn2g, const float* __restrict__ bn2b,
    const float* __restrict__ bn2m, const float* __restrict__ bn2v,
    float* __restrict__ yfin)
{
  const int b = blockIdx.x;
  const int tid = threadIdx.x;
  const int wv = tid >> 6, l = tid & 63;
  __shared__ float rm[32], wts[32], wgt[256];
  for (int kk = wv; kk < 32; kk += 4) {
    const float* er = enh + (size_t)(b * 32 + kk) * 256;
    float s = er[l] + er[l + 64] + er[l + 128] + er[l + 192];
#pragma unroll
    for (int o = 1; o < 64; o <<= 1) s += __shfl_xor(s, o);
    if (l == 0) rm[kk] = s * (1.f / 256.f);
  }
  __syncthreads();
  if (tid < 32) {
    float m = rm[tid];
    float mx = m;
#pragma unroll
    for (int o = 1; o < 32; o <<= 1) mx = fmaxf(mx, __shfl_xor(mx, o, 32));
    float e = __expf(m - mx);
    float sm = e;
#pragma unroll
    for (int o = 1; o < 32; o <<= 1) sm += __shfl_xor(sm, o, 32);
    wts[tid] = e / sm;
  }
  __syncthreads();
  float wsum = 0.f;
  for (int kk = 0; kk < 32; ++kk)
    wsum += enh[(size_t)(b * 32 + kk) * 256 + tid] * wts[kk];
  wgt[tid] = wsum;
  __syncthreads();
  const int co = tid;
  float yv = recb[co];
  for (int ci = 0; ci < 256; ++ci)
    yv += wgt[ci] * recT[ci * 256 + co];
  float s = bn2g[co] / sqrtf(bn2v[co] + EPSV);
  yfin[b * 256 + co] = yv * s + (bn2b[co] - bn2m[co] * s);
}

// ---------------------------------------------------------------------------
// out = x + yfin[b][c] broadcast. Block per (b,c) plane (6400 f32 = 1600 f4).
// ---------------------------------------------------------------------------
__global__ __launch_bounds__(256) void add_kernel(
    const float* __restrict__ x, const float* __restrict__ yfin,
    float* __restrict__ out)
{
  const int bc = blockIdx.x;
  const float a = yfin[bc];
  const f32x4* xp = (const f32x4*)(x + (size_t)bc * 6400);
  f32x4* op = (f32x4*)(out + (size_t)bc * 6400);
  for (int i = threadIdx.x; i < 1600; i += 256) {
    f32x4 v = xp[i];
    v.x += a; v.y += a; v.z += a; v.w += a;
    op[i] = v;
  }
}

extern "C" void kernel_launch(void* const* d_in, const int* in_sizes, int n_in,
                              void* d_out, int out_size, void* d_ws, size_t ws_size,
                              hipStream_t stream)
{
  const float* x      = (const float*)d_in[0];
  const float* boxes  = (const float*)d_in[1];
  const float* conv_w = (const float*)d_in[2];
  const float* conv_b = (const float*)d_in[3];
  const float* bn1g   = (const float*)d_in[4];
  const float* bn1b   = (const float*)d_in[5];
  const float* bn1m   = (const float*)d_in[6];
  const float* bn1v   = (const float*)d_in[7];
  const float* wq     = (const float*)d_in[8];
  const float* bq     = (const float*)d_in[9];
  const float* wk     = (const float*)d_in[10];
  const float* bkp    = (const float*)d_in[11];
  const float* wv     = (const float*)d_in[12];
  const float* bv     = (const float*)d_in[13];
  const float* scale  = (const float*)d_in[14];
  const float* wo     = (const float*)d_in[15];
  const float* bo     = (const float*)d_in[16];
  const float* lng    = (const float*)d_in[17];
  const float* lnb    = (const float*)d_in[18];
  const float* rec_w  = (const float*)d_in[19];
  const float* rec_b  = (const float*)d_in[20];
  const float* bn2g   = (const float*)d_in[21];
  const float* bn2b   = (const float*)d_in[22];
  const float* bn2m   = (const float*)d_in[23];
  const float* bn2v   = (const float*)d_in[24];
  float* out = (float*)d_out;

  char* ws = (char*)d_ws;
  unsigned short* Wr   = (unsigned short*)(ws);                       // 1,179,648 B
  float* wT    = (float*)(ws + 53608448);                             // 1,310,720 B
  float* nodes = (float*)(ws + 54919168);
  float* qb    = nodes + 131072;
  float* kb    = qb + 131072;
  float* vb    = kb + 131072;
  float* enh   = vb + 131072;
  float* yfin  = enh + 131072;                                        // 16 KB

  // xin (NHWC bf16, 52.4 MB) + 1KB zero pad live in d_out scratch — fully
  // consumed by roiconv before add_kernel overwrites d_out. Deterministic:
  // the pad is re-zeroed by prep_convw every call.
  unsigned short* xin = (unsigned short*)d_out;
  float* zpad = (float*)((char*)d_out + 52428800);

  hipLaunchKernelGGL(prep_convw_kernel, dim3(2304), dim3(256), 0, stream,
                     conv_w, Wr, zpad);
  hipLaunchKernelGGL(prep_transpose_kernel, dim3(1280), dim3(256), 0, stream,
                     wq, wk, wv, wo, rec_w, wT);
  hipLaunchKernelGGL(prep_nhwc_kernel, dim3(1280), dim3(256), 0, stream, x, xin);
  hipLaunchKernelGGL(roiconv_kernel, dim3(512), dim3(256), 0, stream,
                     xin, boxes, conv_b, bn1g, bn1b, bn1m, bn1v, Wr, nodes);
  hipLaunchKernelGGL(qkv_kernel, dim3(64), dim3(256), 0, stream,
                     nodes, wT, bq, bkp, bv, qb, kb, vb);
  hipLaunchKernelGGL(attn_kernel, dim3(512), dim3(256), 0, stream,
                     qb, kb, vb, nodes, wT + 3 * 65536, bo, lng, lnb, scale, enh);
  hipLaunchKernelGGL(final_kernel, dim3(16), dim3(256), 0, stream,
                     enh, wT + 4 * 65536, rec_b, bn2g, bn2b, bn2m, bn2v, yfin);
  hipLaunchKernelGGL(add_kernel, dim3(4096), dim3(256), 0, stream, x, yfin, out);
}

// Round 7
// 190.137 us; speedup vs baseline: 2.4874x; 1.0939x over previous
//
#include <hip/hip_runtime.h>

#define EPSV 1e-5f

typedef __attribute__((ext_vector_type(8))) short short8v;
typedef __attribute__((ext_vector_type(4))) float f32x4;

static __device__ __forceinline__ unsigned short f2bf(float f) {
  unsigned int u = __float_as_uint(f);
  u += 0x7fff + ((u >> 16) & 1);
  return (unsigned short)(u >> 16);
}
static __device__ __forceinline__ float bf2f(unsigned short h) {
  return __uint_as_float(((unsigned int)h) << 16);
}

// async global->LDS 16B: dest = wave-uniform base + lane*16 (linear)
static __device__ __forceinline__ void glds16(const void* g, void* l) {
  __builtin_amdgcn_global_load_lds(
      (const __attribute__((address_space(1))) void*)g,
      (__attribute__((address_space(3))) void*)l, 16, 0, 0);
}

// ---------------------------------------------------------------------------
// Fused prep: blocks [0,1280) NCHW->NHWC bf16; [1280,3584) conv-w reorder
// (+zpad zero); [3584,4864) GAT weight transposes.
// ---------------------------------------------------------------------------
__global__ __launch_bounds__(256) void prep_fused_kernel(
    const float* __restrict__ x, unsigned short* __restrict__ xin,
    const float* __restrict__ cw, unsigned short* __restrict__ Wr,
    float* __restrict__ zpad,
    const float* __restrict__ wq, const float* __restrict__ wk,
    const float* __restrict__ wv, const float* __restrict__ wo,
    const float* __restrict__ rec, float* __restrict__ wT)
{
  __shared__ unsigned short t[80 * 257];
  const int bid = blockIdx.x;
  if (bid < 1280) {
    int b = bid / 80, y = bid - b * 80;
    const float* src = x + (size_t)b * 256 * 6400 + y * 80;
    for (int e = threadIdx.x; e < 256 * 20; e += 256) {
      int c = e / 20;
      int px4 = e - c * 20;
      f32x4 v = *(const f32x4*)&src[(size_t)c * 6400 + px4 * 4];
#pragma unroll
      for (int j = 0; j < 4; ++j)
        t[(px4 * 4 + j) * 257 + c] = f2bf(v[j]);
    }
    __syncthreads();
    unsigned short* dst = xin + (size_t)bid * 80 * 256;
    for (int e = threadIdx.x; e < 80 * 32; e += 256) {
      int px = e >> 5;
      int c8 = e & 31;
      short8v v;
#pragma unroll
      for (int j = 0; j < 8; ++j) v[j] = t[px * 257 + c8 * 8 + j];
      *(short8v*)&dst[px * 256 + c8 * 8] = v;
    }
  } else if (bid < 3584) {
    if (bid == 1280) zpad[threadIdx.x] = 0.f;
    int idx = (bid - 1280) * 256 + threadIdx.x;
    int cil = idx & 31;
    int rest = idx >> 5;
    int co = rest & 255;
    int tcc = rest >> 8;
    int cc = tcc & 7;
    int tt = tcc >> 3;
    int dy = tt / 3, dx = tt - dy * 3;
    int ci = cc * 32 + cil;
    Wr[idx] = f2bf(cw[((co * 256 + ci) * 3 + dy) * 3 + dx]);
  } else {
    int idx = (bid - 3584) * 256 + threadIdx.x;
    int m = idx >> 16;
    int e = idx & 65535;
    int ci = e >> 8, co = e & 255;
    const float* src = (m == 0) ? wq : (m == 1) ? wk : (m == 2) ? wv
                     : (m == 3) ? wo : rec;
    wT[idx] = src[co * 256 + ci];
  }
}

// ---------------------------------------------------------------------------
// Fused direct conv@roi-pixels + BN + SiLU + bilinear avg -> nodes[512][256].
// Block per node: M=64 corner px, N=256 co, K=9x256. 4 waves x co64.
// bf16 epilogue buffer (matches R5 feat precision) -> 41.2KB LDS, 3 blk/CU.
// ---------------------------------------------------------------------------
__global__ __launch_bounds__(256, 3) void roiconv_kernel(
    const unsigned short* __restrict__ xin,   // zpad zeros at byte 52428800
    const float* __restrict__ boxes,
    const float* __restrict__ convb,
    const float* __restrict__ bn1g, const float* __restrict__ bn1b,
    const float* __restrict__ bn1m, const float* __restrict__ bn1v,
    const unsigned short* __restrict__ Wr,
    float* __restrict__ nodes)
{
  const int bid = blockIdx.x;
  const int n = (bid & 7) * 64 + (bid >> 3);   // XCD-bijective (512%8==0)
  const int b = n >> 5;
  const int tid = threadIdx.x;
  const int w = tid >> 6, lane = tid & 63;
  const int bq = lane >> 4, r16 = lane & 15;

  // IN0@0 IN1@4096, W0@8192 W1@24576; epilogue bf16 [64][264] = 33792B union
  __shared__ __align__(16) char lds[41216];
  float* wcoef = (float*)(lds + 40960);
  const int IN0 = 0, IN1 = 4096, W0 = 8192, W1 = 24576;

  // ---- geometry for this thread's pixel px = tid>>2 ----
  const int px = tid >> 2;
  const float* bx = boxes + n * 4;
  float x1 = bx[0] * 79.f, y1 = bx[1] * 79.f, x2 = bx[2] * 79.f, y2 = bx[3] * 79.f;
  float rwd = fmaxf(x2 - x1, 1.f), rh = fmaxf(y2 - y1, 1.f);
  int s = px >> 2;
  int sy = s >> 2, sx = s & 3;
  float yy = y1 + (sy + 0.5f) * 0.25f * rh;
  float xx = x1 + (sx + 0.5f) * 0.25f * rwd;
  bool valid = (yy >= -1.f) && (yy <= 80.f) && (xx >= -1.f) && (xx <= 80.f);
  float yc = fminf(fmaxf(yy, 0.f), 79.f), xc = fminf(fmaxf(xx, 0.f), 79.f);
  float y0f = floorf(yc), x0f = floorf(xc);
  int y0i = (int)y0f, x0i = (int)x0f;
  int y1i = min(y0i + 1, 79), x1i = min(x0i + 1, 79);
  float ly = yc - y0f, lx = xc - x0f, hy = 1.f - ly, hx = 1.f - lx;
  int py = (px & 2) ? y1i : y0i;
  int pxx = (px & 1) ? x1i : x0i;
  if ((tid & 3) == 0)
    wcoef[px] = ((px & 2) ? ly : hy) * ((px & 1) ? lx : hx) *
                (valid ? 0.0625f : 0.f);

  // ---- staging source offsets (R5-verified swizzle) ----
  const int chunk = (tid & 3) ^ ((px >> 1) & 3);
  unsigned ioff[9];
#pragma unroll
  for (int t = 0; t < 9; ++t) {
    int dy = t / 3, dx = t - dy * 3;
    int cy = py + dy - 1, cx = pxx + dx - 1;
    bool ok = ((unsigned)cy < 80u) && ((unsigned)cx < 80u);
    ioff[t] = ok ? (unsigned)((((b * 80 + cy) * 80 + cx) * 256 + chunk * 8) * 2)
                 : 52428800u;
  }
  unsigned woff[4];
#pragma unroll
  for (int i = 0; i < 4; ++i) {
    int s2 = tid + (i << 8);
    int wco = s2 >> 2;
    int wch = (s2 & 3) ^ ((wco >> 1) & 3);
    woff[i] = (unsigned)((wco * 32 + wch * 8) * 2);
  }
  const int laneoff = r16 * 64 + ((bq ^ ((r16 >> 1) & 3)) << 4);
  const char* xinb = (const char*)xin;
  const char* Wrb = (const char*)Wr;

  f32x4 acc[4][4];
#pragma unroll
  for (int i = 0; i < 4; ++i)
#pragma unroll
    for (int j = 0; j < 4; ++j)
      acc[i][j] = (f32x4){0.f, 0.f, 0.f, 0.f};

  // prologue: stage step 0 (t=0, cc=0)
  glds16(xinb + ioff[0], lds + IN0 + ((w << 6) << 4));
#pragma unroll
  for (int i = 0; i < 4; ++i)
    glds16(Wrb + woff[i], lds + W0 + (((i << 8) + (w << 6)) << 4));
  __syncthreads();

  for (int cc = 0; cc < 8; ++cc) {
#pragma unroll
    for (int t = 0; t < 9; ++t) {
      const int step = cc * 9 + t;
      const char* inb = lds + ((step & 1) ? IN1 : IN0);
      const char* wb  = lds + ((step & 1) ? W1 : W0);
      char* innx = lds + ((step & 1) ? IN0 : IN1);
      char* wbn  = lds + ((step & 1) ? W0 : W1);
      if (step < 71) {
        const int nt = (t == 8) ? 0 : t + 1;
        const int ncc = (t == 8) ? cc + 1 : cc;
        glds16(xinb + ioff[nt] + ncc * 64, innx + ((w << 6) << 4));
        const char* wg = Wrb + ((size_t)(nt * 8 + ncc) << 14);
#pragma unroll
        for (int i = 0; i < 4; ++i)
          glds16(wg + woff[i], wbn + (((i << 8) + (w << 6)) << 4));
      }
      const char* pa = inb + laneoff;
      const char* pw = wb + w * 4096 + laneoff;
      short8v af0 = *(const short8v*)(pa);
      short8v af1 = *(const short8v*)(pa + 1024);
      short8v af2 = *(const short8v*)(pa + 2048);
      short8v af3 = *(const short8v*)(pa + 3072);
      short8v wf0 = *(const short8v*)(pw);
      short8v wf1 = *(const short8v*)(pw + 1024);
      short8v wf2 = *(const short8v*)(pw + 2048);
      short8v wf3 = *(const short8v*)(pw + 3072);
      __builtin_amdgcn_s_setprio(1);
      acc[0][0] = __builtin_amdgcn_mfma_f32_16x16x32_bf16(af0, wf0, acc[0][0], 0, 0, 0);
      acc[0][1] = __builtin_amdgcn_mfma_f32_16x16x32_bf16(af0, wf1, acc[0][1], 0, 0, 0);
      acc[0][2] = __builtin_amdgcn_mfma_f32_16x16x32_bf16(af0, wf2, acc[0][2], 0, 0, 0);
      acc[0][3] = __builtin_amdgcn_mfma_f32_16x16x32_bf16(af0, wf3, acc[0][3], 0, 0, 0);
      acc[1][0] = __builtin_amdgcn_mfma_f32_16x16x32_bf16(af1, wf0, acc[1][0], 0, 0, 0);
      acc[1][1] = __builtin_amdgcn_mfma_f32_16x16x32_bf16(af1, wf1, acc[1][1], 0, 0, 0);
      acc[1][2] = __builtin_amdgcn_mfma_f32_16x16x32_bf16(af1, wf2, acc[1][2], 0, 0, 0);
      acc[1][3] = __builtin_amdgcn_mfma_f32_16x16x32_bf16(af1, wf3, acc[1][3], 0, 0, 0);
      acc[2][0] = __builtin_amdgcn_mfma_f32_16x16x32_bf16(af2, wf0, acc[2][0], 0, 0, 0);
      acc[2][1] = __builtin_amdgcn_mfma_f32_16x16x32_bf16(af2, wf1, acc[2][1], 0, 0, 0);
      acc[2][2] = __builtin_amdgcn_mfma_f32_16x16x32_bf16(af2, wf2, acc[2][2], 0, 0, 0);
      acc[2][3] = __builtin_amdgcn_mfma_f32_16x16x32_bf16(af2, wf3, acc[2][3], 0, 0, 0);
      acc[3][0] = __builtin_amdgcn_mfma_f32_16x16x32_bf16(af3, wf0, acc[3][0], 0, 0, 0);
      acc[3][1] = __builtin_amdgcn_mfma_f32_16x16x32_bf16(af3, wf1, acc[3][1], 0, 0, 0);
      acc[3][2] = __builtin_amdgcn_mfma_f32_16x16x32_bf16(af3, wf2, acc[3][2], 0, 0, 0);
      acc[3][3] = __builtin_amdgcn_mfma_f32_16x16x32_bf16(af3, wf3, acc[3][3], 0, 0, 0);
      __builtin_amdgcn_s_setprio(0);
      __syncthreads();
    }
  }

  // epilogue: bias+BN+SiLU -> bf16 ep[64][264]; then bilinear combine (f32)
  unsigned short* ep = (unsigned short*)lds;
#pragma unroll
  for (int cf = 0; cf < 4; ++cf) {
    int co = w * 64 + cf * 16 + r16;
    float sc = bn1g[co] / sqrtf(bn1v[co] + EPSV);
    float sh = bn1b[co] - bn1m[co] * sc;
    float cb = convb[co];
#pragma unroll
    for (int mf = 0; mf < 4; ++mf) {
#pragma unroll
      for (int rg = 0; rg < 4; ++rg) {
        int pxo = mf * 16 + bq * 4 + rg;    // D row = 4*(lane>>4)+reg (m89)
        float v = (acc[mf][cf][rg] + cb) * sc + sh;
        v = v / (1.f + __expf(-v));         // SiLU
        ep[pxo * 264 + co] = f2bf(v);
      }
    }
  }
  __syncthreads();
  const int c = tid;
  float val = 0.f;
#pragma unroll
  for (int p = 0; p < 64; ++p)
    val += wcoef[p] * bf2f(ep[p * 264 + c]);
  nodes[n * 256 + c] = val;
}

// ---------------------------------------------------------------------------
// q,k,v projections. Block handles 8 nodes; thread = output channel.
// ---------------------------------------------------------------------------
__global__ __launch_bounds__(256) void qkv_kernel(
    const float* __restrict__ nodes, const float* __restrict__ wT,
    const float* __restrict__ bq, const float* __restrict__ bk,
    const float* __restrict__ bv,
    float* __restrict__ q, float* __restrict__ k, float* __restrict__ v)
{
  const int blk = blockIdx.x;
  const int co = threadIdx.x;
  __shared__ float nd[8][256];
  for (int i = threadIdx.x; i < 2048; i += 256)
    nd[i >> 8][i & 255] = nodes[blk * 2048 + i];
  __syncthreads();
  float aq[8] = {0,0,0,0,0,0,0,0};
  float ak[8] = {0,0,0,0,0,0,0,0};
  float av[8] = {0,0,0,0,0,0,0,0};
  const float* wqT = wT;
  const float* wkT = wT + 65536;
  const float* wvT = wT + 131072;
  for (int ci = 0; ci < 256; ++ci) {
    float wq_ = wqT[ci * 256 + co];
    float wk_ = wkT[ci * 256 + co];
    float wv_ = wvT[ci * 256 + co];
#pragma unroll
    for (int r = 0; r < 8; ++r) {
      float nv = nd[r][ci];
      aq[r] += nv * wq_;
      ak[r] += nv * wk_;
      av[r] += nv * wv_;
    }
  }
  float bq_ = bq[co], bk_ = bk[co], bv_ = bv[co];
#pragma unroll
  for (int r = 0; r < 8; ++r) {
    int n = blk * 8 + r;
    q[n * 256 + co] = aq[r] + bq_;
    k[n * 256 + co] = ak[r] + bk_;
    v[n * 256 + co] = av[r] + bv_;
  }
}

// ---------------------------------------------------------------------------
// Multi-head attention core: block per (head, 16-query chunk) = 256 blocks.
// K_h, V_h staged in LDS [512][32] f32 with chunk-XOR swizzle (~2-way free).
// Scores in regs (32/thread), softmax via 16-wide shfl, P bf16 in LDS,
// PV per (query, d-pair) -> msgs[512][256].
// ---------------------------------------------------------------------------
__global__ __launch_bounds__(256) void attn_mh_kernel(
    const float* __restrict__ q, const float* __restrict__ k,
    const float* __restrict__ v, const float* __restrict__ scale_p,
    float* __restrict__ msgs)
{
  const int bid = blockIdx.x;
  const int h = bid & 7, qc = bid >> 3;       // qc 0..31
  const int q0 = qc * 16;
  const int tid = threadIdx.x;
  __shared__ __align__(16) float Kh[512 * 32];
  __shared__ __align__(16) float Vh[512 * 32];
  __shared__ unsigned short pb[16 * 512];

  for (int idx = tid; idx < 4096; idx += 256) {
    int j = idx >> 3, part = idx & 7;
    int chs = part ^ (j & 7);
    *(f32x4*)&Kh[j * 32 + chs * 4] =
        *(const f32x4*)&k[(size_t)j * 256 + h * 32 + part * 4];
    *(f32x4*)&Vh[j * 32 + chs * 4] =
        *(const f32x4*)&v[(size_t)j * 256 + h * 32 + part * 4];
  }
  const int qi = tid >> 4, l = tid & 15;
  f32x4 qr[8];
#pragma unroll
  for (int p = 0; p < 8; ++p)
    qr[p] = *(const f32x4*)&q[(size_t)(q0 + qi) * 256 + h * 32 + p * 4];
  const float scale = scale_p[0];
  __syncthreads();

  float pj[32];
  float mx = -1e30f;
#pragma unroll
  for (int jj = 0; jj < 32; ++jj) {
    int j = jj * 16 + l;
    const float* kr = &Kh[j * 32];
    int sw = j & 7;
    float s = 0.f;
#pragma unroll
    for (int p = 0; p < 8; ++p) {
      f32x4 kv = *(const f32x4*)&kr[(p ^ sw) * 4];
      s += kv.x * qr[p].x + kv.y * qr[p].y + kv.z * qr[p].z + kv.w * qr[p].w;
    }
    s *= scale;
    pj[jj] = s;
    mx = fmaxf(mx, s);
  }
#pragma unroll
  for (int o = 1; o < 16; o <<= 1) mx = fmaxf(mx, __shfl_xor(mx, o, 16));
  float sum = 0.f;
#pragma unroll
  for (int jj = 0; jj < 32; ++jj) {
    float e = __expf(pj[jj] - mx);
    pj[jj] = e;
    sum += e;
  }
#pragma unroll
  for (int o = 1; o < 16; o <<= 1) sum += __shfl_xor(sum, o, 16);
  float inv = 1.f / sum;
#pragma unroll
  for (int jj = 0; jj < 32; ++jj)
    pb[qi * 512 + jj * 16 + l] = f2bf(pj[jj] * inv);
  __syncthreads();

  // PV: thread (qi, d-pair l): d0 = 2l
  float m0 = 0.f, m1 = 0.f;
  const unsigned short* pq = &pb[qi * 512];
  for (int j = 0; j < 512; ++j) {
    float p = bf2f(pq[j]);
    int chs = (l >> 1) ^ (j & 7);
    const float* vr = &Vh[j * 32 + chs * 4 + ((2 * l) & 3)];
    m0 += p * vr[0];
    m1 += p * vr[1];
  }
  float* mo = &msgs[(size_t)(q0 + qi) * 256 + h * 32 + 2 * l];
  mo[0] = m0;
  mo[1] = m1;
}

// ---------------------------------------------------------------------------
// Out-proj + residual + LayerNorm. Block per 8 nodes (amortizes wo reads).
// ---------------------------------------------------------------------------
__global__ __launch_bounds__(256) void outln_kernel(
    const float* __restrict__ msgs, const float* __restrict__ nodes,
    const float* __restrict__ woT, const float* __restrict__ bo,
    const float* __restrict__ lng, const float* __restrict__ lnb,
    float* __restrict__ enh)
{
  const int blk = blockIdx.x;
  const int co = threadIdx.x;
  __shared__ float ms[8][256];
  __shared__ float red1[8][4], red2[8][4];
  for (int i = co; i < 2048; i += 256)
    ms[i >> 8][i & 255] = msgs[blk * 2048 + i];
  __syncthreads();
  float yv[8];
  float bo_ = bo[co];
#pragma unroll
  for (int r = 0; r < 8; ++r)
    yv[r] = nodes[(size_t)(blk * 8 + r) * 256 + co] + bo_;
  for (int ci = 0; ci < 256; ++ci) {
    float w = woT[ci * 256 + co];
#pragma unroll
    for (int r = 0; r < 8; ++r) yv[r] += ms[r][ci] * w;
  }
  const int wv = co >> 6, lane = co & 63;
#pragma unroll
  for (int r = 0; r < 8; ++r) {
    float s1 = yv[r], s2 = yv[r] * yv[r];
#pragma unroll
    for (int o = 1; o < 64; o <<= 1) {
      s1 += __shfl_xor(s1, o);
      s2 += __shfl_xor(s2, o);
    }
    if (lane == 0) { red1[r][wv] = s1; red2[r][wv] = s2; }
  }
  __syncthreads();
  float lg = lng[co], lb = lnb[co];
#pragma unroll
  for (int r = 0; r < 8; ++r) {
    float S1 = red1[r][0] + red1[r][1] + red1[r][2] + red1[r][3];
    float S2 = red2[r][0] + red2[r][1] + red2[r][2] + red2[r][3];
    float mu = S1 * (1.f / 256.f);
    float var = S2 * (1.f / 256.f) - mu * mu;
    enh[(size_t)(blk * 8 + r) * 256 + co] =
        (yv[r] - mu) * rsqrtf(var + EPSV) * lg + lb;
  }
}

// ---------------------------------------------------------------------------
// Per-batch pooling + rec 1x1 conv + BN2 -> yfin[b][c]. Block per batch.
// ---------------------------------------------------------------------------
__global__ __launch_bounds__(256) void final_kernel(
    const float* __restrict__ enh, const float* __restrict__ recT,
    const float* __restrict__ recb,
    const float* __restrict__ bn2g, const float* __restrict__ bn2b,
    const float* __restrict__ bn2m, const float* __restrict__ bn2v,
    float* __restrict__ yfin)
{
  const int b = blockIdx.x;
  const int tid = threadIdx.x;
  const int wv = tid >> 6, l = tid & 63;
  __shared__ float rm[32], wts[32], wgt[256];
  for (int kk = wv; kk < 32; kk += 4) {
    const float* er = enh + (size_t)(b * 32 + kk) * 256;
    float s = er[l] + er[l + 64] + er[l + 128] + er[l + 192];
#pragma unroll
    for (int o = 1; o < 64; o <<= 1) s += __shfl_xor(s, o);
    if (l == 0) rm[kk] = s * (1.f / 256.f);
  }
  __syncthreads();
  if (tid < 32) {
    float m = rm[tid];
    float mx = m;
#pragma unroll
    for (int o = 1; o < 32; o <<= 1) mx = fmaxf(mx, __shfl_xor(mx, o, 32));
    float e = __expf(m - mx);
    float sm = e;
#pragma unroll
    for (int o = 1; o < 32; o <<= 1) sm += __shfl_xor(sm, o, 32);
    wts[tid] = e / sm;
  }
  __syncthreads();
  float wsum = 0.f;
  for (int kk = 0; kk < 32; ++kk)
    wsum += enh[(size_t)(b * 32 + kk) * 256 + tid] * wts[kk];
  wgt[tid] = wsum;
  __syncthreads();
  const int co = tid;
  float yv = recb[co];
  for (int ci = 0; ci < 256; ++ci)
    yv += wgt[ci] * recT[ci * 256 + co];
  float s = bn2g[co] / sqrtf(bn2v[co] + EPSV);
  yfin[b * 256 + co] = yv * s + (bn2b[co] - bn2m[co] * s);
}

// ---------------------------------------------------------------------------
// out = x + yfin[b][c] broadcast. Block per (b,c) plane (6400 f32 = 1600 f4).
// ---------------------------------------------------------------------------
__global__ __launch_bounds__(256) void add_kernel(
    const float* __restrict__ x, const float* __restrict__ yfin,
    float* __restrict__ out)
{
  const int bc = blockIdx.x;
  const float a = yfin[bc];
  const f32x4* xp = (const f32x4*)(x + (size_t)bc * 6400);
  f32x4* op = (f32x4*)(out + (size_t)bc * 6400);
  for (int i = threadIdx.x; i < 1600; i += 256) {
    f32x4 v = xp[i];
    v.x += a; v.y += a; v.z += a; v.w += a;
    op[i] = v;
  }
}

extern "C" void kernel_launch(void* const* d_in, const int* in_sizes, int n_in,
                              void* d_out, int out_size, void* d_ws, size_t ws_size,
                              hipStream_t stream)
{
  const float* x      = (const float*)d_in[0];
  const float* boxes  = (const float*)d_in[1];
  const float* conv_w = (const float*)d_in[2];
  const float* conv_b = (const float*)d_in[3];
  const float* bn1g   = (const float*)d_in[4];
  const float* bn1b   = (const float*)d_in[5];
  const float* bn1m   = (const float*)d_in[6];
  const float* bn1v   = (const float*)d_in[7];
  const float* wq     = (const float*)d_in[8];
  const float* bq     = (const float*)d_in[9];
  const float* wk     = (const float*)d_in[10];
  const float* bkp    = (const float*)d_in[11];
  const float* wv     = (const float*)d_in[12];
  const float* bv     = (const float*)d_in[13];
  const float* scale  = (const float*)d_in[14];
  const float* wo     = (const float*)d_in[15];
  const float* bo     = (const float*)d_in[16];
  const float* lng    = (const float*)d_in[17];
  const float* lnb    = (const float*)d_in[18];
  const float* rec_w  = (const float*)d_in[19];
  const float* rec_b  = (const float*)d_in[20];
  const float* bn2g   = (const float*)d_in[21];
  const float* bn2b   = (const float*)d_in[22];
  const float* bn2m   = (const float*)d_in[23];
  const float* bn2v   = (const float*)d_in[24];
  float* out = (float*)d_out;

  char* ws = (char*)d_ws;
  unsigned short* Wr = (unsigned short*)(ws);                // 1,179,648 B
  float* wT    = (float*)(ws + 53608448);                    // 1,310,720 B
  float* nodes = (float*)(ws + 54919168);
  float* qb    = nodes + 131072;
  float* kb    = qb + 131072;
  float* vb    = kb + 131072;
  float* enh   = vb + 131072;
  float* yfin  = enh + 131072;                               // 16 KB
  float* msgs  = yfin + 4096;                                // 512 KB

  // xin (NHWC bf16, 52.4 MB) + 1KB zero pad live in d_out scratch — fully
  // consumed by roiconv before add_kernel overwrites d_out. Deterministic:
  // the pad is re-zeroed by prep_fused every call.
  unsigned short* xin = (unsigned short*)d_out;
  float* zpad = (float*)((char*)d_out + 52428800);

  hipLaunchKernelGGL(prep_fused_kernel, dim3(4864), dim3(256), 0, stream,
                     x, xin, conv_w, Wr, zpad, wq, wk, wv, wo, rec_w, wT);
  hipLaunchKernelGGL(roiconv_kernel, dim3(512), dim3(256), 0, stream,
                     xin, boxes, conv_b, bn1g, bn1b, bn1m, bn1v, Wr, nodes);
  hipLaunchKernelGGL(qkv_kernel, dim3(64), dim3(256), 0, stream,
                     nodes, wT, bq, bkp, bv, qb, kb, vb);
  hipLaunchKernelGGL(attn_mh_kernel, dim3(256), dim3(256), 0, stream,
                     qb, kb, vb, scale, msgs);
  hipLaunchKernelGGL(outln_kernel, dim3(64), dim3(256), 0, stream,
                     msgs, nodes, wT + 3 * 65536, bo, lng, lnb, enh);
  hipLaunchKernelGGL(final_kernel, dim3(16), dim3(256), 0, stream,
                     enh, wT + 4 * 65536, rec_b, bn2g, bn2b, bn2m, bn2v, yfin);
  hipLaunchKernelGGL(add_kernel, dim3(4096), dim3(256), 0, stream, x, yfin, out);
}

// Round 8
// 186.652 us; speedup vs baseline: 2.5338x; 1.0187x over previous
//
#include <hip/hip_runtime.h>

#define EPSV 1e-5f

typedef __attribute__((ext_vector_type(8))) short short8v;
typedef __attribute__((ext_vector_type(4))) float f32x4;

static __device__ __forceinline__ unsigned short f2bf(float f) {
  unsigned int u = __float_as_uint(f);
  u += 0x7fff + ((u >> 16) & 1);
  return (unsigned short)(u >> 16);
}
static __device__ __forceinline__ float bf2f(unsigned short h) {
  return __uint_as_float(((unsigned int)h) << 16);
}

// async global->LDS 16B: dest = wave-uniform base + lane*16 (linear)
static __device__ __forceinline__ void glds16(const void* g, void* l) {
  __builtin_amdgcn_global_load_lds(
      (const __attribute__((address_space(1))) void*)g,
      (__attribute__((address_space(3))) void*)l, 16, 0, 0);
}

// ---------------------------------------------------------------------------
// Fused prep: blocks [0,1280) NCHW->NHWC bf16; [1280,3584) conv-w reorder
// (+zpad zero); [3584,4864) GAT weight transposes.
// ---------------------------------------------------------------------------
__global__ __launch_bounds__(256) void prep_fused_kernel(
    const float* __restrict__ x, unsigned short* __restrict__ xin,
    const float* __restrict__ cw, unsigned short* __restrict__ Wr,
    float* __restrict__ zpad,
    const float* __restrict__ wq, const float* __restrict__ wk,
    const float* __restrict__ wv, const float* __restrict__ wo,
    const float* __restrict__ rec, float* __restrict__ wT)
{
  __shared__ unsigned short t[80 * 257];
  const int bid = blockIdx.x;
  if (bid < 1280) {
    int b = bid / 80, y = bid - b * 80;
    const float* src = x + (size_t)b * 256 * 6400 + y * 80;
    for (int e = threadIdx.x; e < 256 * 20; e += 256) {
      int c = e / 20;
      int px4 = e - c * 20;
      f32x4 v = *(const f32x4*)&src[(size_t)c * 6400 + px4 * 4];
#pragma unroll
      for (int j = 0; j < 4; ++j)
        t[(px4 * 4 + j) * 257 + c] = f2bf(v[j]);
    }
    __syncthreads();
    unsigned short* dst = xin + (size_t)bid * 80 * 256;
    for (int e = threadIdx.x; e < 80 * 32; e += 256) {
      int px = e >> 5;
      int c8 = e & 31;
      short8v v;
#pragma unroll
      for (int j = 0; j < 8; ++j) v[j] = t[px * 257 + c8 * 8 + j];
      *(short8v*)&dst[px * 256 + c8 * 8] = v;
    }
  } else if (bid < 3584) {
    if (bid == 1280) zpad[threadIdx.x] = 0.f;
    int idx = (bid - 1280) * 256 + threadIdx.x;
    int cil = idx & 31;
    int rest = idx >> 5;
    int co = rest & 255;
    int tcc = rest >> 8;
    int cc = tcc & 7;
    int tt = tcc >> 3;
    int dy = tt / 3, dx = tt - dy * 3;
    int ci = cc * 32 + cil;
    Wr[idx] = f2bf(cw[((co * 256 + ci) * 3 + dy) * 3 + dx]);
  } else {
    int idx = (bid - 3584) * 256 + threadIdx.x;
    int m = idx >> 16;
    int e = idx & 65535;
    int ci = e >> 8, co = e & 255;
    const float* src = (m == 0) ? wq : (m == 1) ? wk : (m == 2) ? wv
                     : (m == 3) ? wo : rec;
    wT[idx] = src[co * 256 + ci];
  }
}

// ---------------------------------------------------------------------------
// Fused direct conv@roi-pixels + BN + SiLU + bilinear avg -> nodes[512][256].
// Block per node: M=64 corner px, N=256 co, K=9x256. 4 waves x co64.
// T3/T4: 3-deep LDS buffer rotation (buf = t%3, since 9%3==0), counted
// s_waitcnt vmcnt(5) + raw s_barrier -> prefetched loads stay in flight
// across barriers with 2 full steps to complete. One barrier per step.
// ---------------------------------------------------------------------------
__global__ __launch_bounds__(256, 2) void roiconv_kernel(
    const unsigned short* __restrict__ xin,   // zpad zeros at byte 52428800
    const float* __restrict__ boxes,
    const float* __restrict__ convb,
    const float* __restrict__ bn1g, const float* __restrict__ bn1b,
    const float* __restrict__ bn1m, const float* __restrict__ bn1v,
    const unsigned short* __restrict__ Wr,
    float* __restrict__ nodes)
{
  const int bid = blockIdx.x;
  const int n = (bid & 7) * 64 + (bid >> 3);   // XCD-bijective (512%8==0)
  const int b = n >> 5;
  const int tid = threadIdx.x;
  const int w = tid >> 6, lane = tid & 63;
  const int bq = lane >> 4, r16 = lane & 15;

  // IN bufs: 3 x 4096 @ 0/4096/8192; W bufs: 3 x 16384 @ 12288/28672/45056;
  // wcoef @ 61440. Epilogue bf16 ep[64][264] = 33792B reuses bytes 0..33791.
  __shared__ __align__(16) char lds[61696];
  float* wcoef = (float*)(lds + 61440);

  // ---- geometry for this thread's pixel px = tid>>2 ----
  const int px = tid >> 2;
  const float* bx = boxes + n * 4;
  float x1 = bx[0] * 79.f, y1 = bx[1] * 79.f, x2 = bx[2] * 79.f, y2 = bx[3] * 79.f;
  float rwd = fmaxf(x2 - x1, 1.f), rh = fmaxf(y2 - y1, 1.f);
  int s = px >> 2;
  int sy = s >> 2, sx = s & 3;
  float yy = y1 + (sy + 0.5f) * 0.25f * rh;
  float xx = x1 + (sx + 0.5f) * 0.25f * rwd;
  bool valid = (yy >= -1.f) && (yy <= 80.f) && (xx >= -1.f) && (xx <= 80.f);
  float yc = fminf(fmaxf(yy, 0.f), 79.f), xc = fminf(fmaxf(xx, 0.f), 79.f);
  float y0f = floorf(yc), x0f = floorf(xc);
  int y0i = (int)y0f, x0i = (int)x0f;
  int y1i = min(y0i + 1, 79), x1i = min(x0i + 1, 79);
  float ly = yc - y0f, lx = xc - x0f, hy = 1.f - ly, hx = 1.f - lx;
  int py = (px & 2) ? y1i : y0i;
  int pxx = (px & 1) ? x1i : x0i;
  if ((tid & 3) == 0)
    wcoef[px] = ((px & 2) ? ly : hy) * ((px & 1) ? lx : hx) *
                (valid ? 0.0625f : 0.f);

  // ---- staging source offsets (R5-verified swizzle) ----
  const int chunk = (tid & 3) ^ ((px >> 1) & 3);
  unsigned ioff[9];
#pragma unroll
  for (int t = 0; t < 9; ++t) {
    int dy = t / 3, dx = t - dy * 3;
    int cy = py + dy - 1, cx = pxx + dx - 1;
    bool ok = ((unsigned)cy < 80u) && ((unsigned)cx < 80u);
    ioff[t] = ok ? (unsigned)((((b * 80 + cy) * 80 + cx) * 256 + chunk * 8) * 2)
                 : 52428800u;
  }
  unsigned woff[4];
#pragma unroll
  for (int i = 0; i < 4; ++i) {
    int s2 = tid + (i << 8);
    int wco = s2 >> 2;
    int wch = (s2 & 3) ^ ((wco >> 1) & 3);
    woff[i] = (unsigned)((wco * 32 + wch * 8) * 2);
  }
  const int laneoff = r16 * 64 + ((bq ^ ((r16 >> 1) & 3)) << 4);
  const char* xinb = (const char*)xin;
  const char* Wrb = (const char*)Wr;
  const int ldst_in = (w << 6) << 4;

  f32x4 acc[4][4];
#pragma unroll
  for (int i = 0; i < 4; ++i)
#pragma unroll
    for (int j = 0; j < 4; ++j)
      acc[i][j] = (f32x4){0.f, 0.f, 0.f, 0.f};

  // prologue: issue steps 0 (t=0,cc=0 -> buf0) and 1 (t=1,cc=0 -> buf1)
  glds16(xinb + ioff[0], lds + 0 + ldst_in);
#pragma unroll
  for (int i = 0; i < 4; ++i)
    glds16(Wrb + woff[i], lds + 12288 + (((i << 8) + (w << 6)) << 4));
  glds16(xinb + ioff[1], lds + 4096 + ldst_in);
#pragma unroll
  for (int i = 0; i < 4; ++i)
    glds16(Wrb + ((size_t)8 << 14) + woff[i],
           lds + 28672 + (((i << 8) + (w << 6)) << 4));

  for (int cc = 0; cc < 8; ++cc) {
#pragma unroll
    for (int t = 0; t < 9; ++t) {
      const int cb = t % 3;                     // compile-time buffer index
      const char* inb = lds + cb * 4096;
      const char* wb  = lds + 12288 + cb * 16384;
      // counted wait: keep newest 5 (step+1) in flight; tail drains fully
      if (cc == 7 && t == 8)
        asm volatile("s_waitcnt vmcnt(0)" ::: "memory");
      else
        asm volatile("s_waitcnt vmcnt(5)" ::: "memory");
      __builtin_amdgcn_s_barrier();
      __builtin_amdgcn_sched_barrier(0);
      // issue step+2 (buffer (t+2)%3, last read at step-1 -> barrier-ordered)
      if (!(cc == 7 && t >= 7)) {
        const int nt = (t + 2 > 8) ? t - 7 : t + 2;   // compile-time
        const int nb = nt % 3;
        const int ncc = cc + (t >= 7 ? 1 : 0);
        char* innx = lds + nb * 4096;
        char* wbn  = lds + 12288 + nb * 16384;
        glds16(xinb + ioff[nt] + ncc * 64, innx + ldst_in);
        const char* wg = Wrb + ((size_t)(nt * 8 + ncc) << 14);
#pragma unroll
        for (int i = 0; i < 4; ++i)
          glds16(wg + woff[i], wbn + (((i << 8) + (w << 6)) << 4));
      }
      const char* pa = inb + laneoff;
      const char* pw = wb + w * 4096 + laneoff;
      short8v af0 = *(const short8v*)(pa);
      short8v af1 = *(const short8v*)(pa + 1024);
      short8v af2 = *(const short8v*)(pa + 2048);
      short8v af3 = *(const short8v*)(pa + 3072);
      short8v wf0 = *(const short8v*)(pw);
      short8v wf1 = *(const short8v*)(pw + 1024);
      short8v wf2 = *(const short8v*)(pw + 2048);
      short8v wf3 = *(const short8v*)(pw + 3072);
      __builtin_amdgcn_s_setprio(1);
      acc[0][0] = __builtin_amdgcn_mfma_f32_16x16x32_bf16(af0, wf0, acc[0][0], 0, 0, 0);
      acc[0][1] = __builtin_amdgcn_mfma_f32_16x16x32_bf16(af0, wf1, acc[0][1], 0, 0, 0);
      acc[0][2] = __builtin_amdgcn_mfma_f32_16x16x32_bf16(af0, wf2, acc[0][2], 0, 0, 0);
      acc[0][3] = __builtin_amdgcn_mfma_f32_16x16x32_bf16(af0, wf3, acc[0][3], 0, 0, 0);
      acc[1][0] = __builtin_amdgcn_mfma_f32_16x16x32_bf16(af1, wf0, acc[1][0], 0, 0, 0);
      acc[1][1] = __builtin_amdgcn_mfma_f32_16x16x32_bf16(af1, wf1, acc[1][1], 0, 0, 0);
      acc[1][2] = __builtin_amdgcn_mfma_f32_16x16x32_bf16(af1, wf2, acc[1][2], 0, 0, 0);
      acc[1][3] = __builtin_amdgcn_mfma_f32_16x16x32_bf16(af1, wf3, acc[1][3], 0, 0, 0);
      acc[2][0] = __builtin_amdgcn_mfma_f32_16x16x32_bf16(af2, wf0, acc[2][0], 0, 0, 0);
      acc[2][1] = __builtin_amdgcn_mfma_f32_16x16x32_bf16(af2, wf1, acc[2][1], 0, 0, 0);
      acc[2][2] = __builtin_amdgcn_mfma_f32_16x16x32_bf16(af2, wf2, acc[2][2], 0, 0, 0);
      acc[2][3] = __builtin_amdgcn_mfma_f32_16x16x32_bf16(af2, wf3, acc[2][3], 0, 0, 0);
      acc[3][0] = __builtin_amdgcn_mfma_f32_16x16x32_bf16(af3, wf0, acc[3][0], 0, 0, 0);
      acc[3][1] = __builtin_amdgcn_mfma_f32_16x16x32_bf16(af3, wf1, acc[3][1], 0, 0, 0);
      acc[3][2] = __builtin_amdgcn_mfma_f32_16x16x32_bf16(af3, wf2, acc[3][2], 0, 0, 0);
      acc[3][3] = __builtin_amdgcn_mfma_f32_16x16x32_bf16(af3, wf3, acc[3][3], 0, 0, 0);
      __builtin_amdgcn_s_setprio(0);
    }
  }
  asm volatile("s_waitcnt vmcnt(0)" ::: "memory");
  __syncthreads();

  // epilogue: bias+BN+SiLU -> bf16 ep[64][264]; then bilinear combine (f32)
  unsigned short* ep = (unsigned short*)lds;
#pragma unroll
  for (int cf = 0; cf < 4; ++cf) {
    int co = w * 64 + cf * 16 + r16;
    float sc = bn1g[co] / sqrtf(bn1v[co] + EPSV);
    float sh = bn1b[co] - bn1m[co] * sc;
    float cb = convb[co];
#pragma unroll
    for (int mf = 0; mf < 4; ++mf) {
#pragma unroll
      for (int rg = 0; rg < 4; ++rg) {
        int pxo = mf * 16 + bq * 4 + rg;    // D row = 4*(lane>>4)+reg (m89)
        float v = (acc[mf][cf][rg] + cb) * sc + sh;
        v = v / (1.f + __expf(-v));         // SiLU
        ep[pxo * 264 + co] = f2bf(v);
      }
    }
  }
  __syncthreads();
  const int c = tid;
  float val = 0.f;
#pragma unroll
  for (int p = 0; p < 64; ++p)
    val += wcoef[p] * bf2f(ep[p * 264 + c]);
  nodes[n * 256 + c] = val;
}

// ---------------------------------------------------------------------------
// q,k,v projections. Block handles 4 nodes (grid 128); thread = out channel.
// ---------------------------------------------------------------------------
__global__ __launch_bounds__(256) void qkv_kernel(
    const float* __restrict__ nodes, const float* __restrict__ wT,
    const float* __restrict__ bq, const float* __restrict__ bk,
    const float* __restrict__ bv,
    float* __restrict__ q, float* __restrict__ k, float* __restrict__ v)
{
  const int blk = blockIdx.x;
  const int co = threadIdx.x;
  __shared__ float nd[4][256];
  for (int i = threadIdx.x; i < 1024; i += 256)
    nd[i >> 8][i & 255] = nodes[blk * 1024 + i];
  __syncthreads();
  float aq[4] = {0, 0, 0, 0};
  float ak[4] = {0, 0, 0, 0};
  float av[4] = {0, 0, 0, 0};
  const float* wqT = wT;
  const float* wkT = wT + 65536;
  const float* wvT = wT + 131072;
  for (int ci = 0; ci < 256; ++ci) {
    float wq_ = wqT[ci * 256 + co];
    float wk_ = wkT[ci * 256 + co];
    float wv_ = wvT[ci * 256 + co];
#pragma unroll
    for (int r = 0; r < 4; ++r) {
      float nv = nd[r][ci];
      aq[r] += nv * wq_;
      ak[r] += nv * wk_;
      av[r] += nv * wv_;
    }
  }
  float bq_ = bq[co], bk_ = bk[co], bv_ = bv[co];
#pragma unroll
  for (int r = 0; r < 4; ++r) {
    int n = blk * 4 + r;
    q[n * 256 + co] = aq[r] + bq_;
    k[n * 256 + co] = ak[r] + bk_;
    v[n * 256 + co] = av[r] + bv_;
  }
}

// ---------------------------------------------------------------------------
// Multi-head attention core: block per (head, 16-query chunk) = 256 blocks.
// K_h, V_h staged in LDS [512][32] f32 with chunk-XOR swizzle (~2-way free).
// Scores in regs (32/thread), softmax via 16-wide shfl, P bf16 in LDS,
// PV per (query, d-pair) -> msgs[512][256].
// ---------------------------------------------------------------------------
__global__ __launch_bounds__(256) void attn_mh_kernel(
    const float* __restrict__ q, const float* __restrict__ k,
    const float* __restrict__ v, const float* __restrict__ scale_p,
    float* __restrict__ msgs)
{
  const int bid = blockIdx.x;
  const int h = bid & 7, qc = bid >> 3;       // qc 0..31
  const int q0 = qc * 16;
  const int tid = threadIdx.x;
  __shared__ __align__(16) float Kh[512 * 32];
  __shared__ __align__(16) float Vh[512 * 32];
  __shared__ unsigned short pb[16 * 512];

  for (int idx = tid; idx < 4096; idx += 256) {
    int j = idx >> 3, part = idx & 7;
    int chs = part ^ (j & 7);
    *(f32x4*)&Kh[j * 32 + chs * 4] =
        *(const f32x4*)&k[(size_t)j * 256 + h * 32 + part * 4];
    *(f32x4*)&Vh[j * 32 + chs * 4] =
        *(const f32x4*)&v[(size_t)j * 256 + h * 32 + part * 4];
  }
  const int qi = tid >> 4, l = tid & 15;
  f32x4 qr[8];
#pragma unroll
  for (int p = 0; p < 8; ++p)
    qr[p] = *(const f32x4*)&q[(size_t)(q0 + qi) * 256 + h * 32 + p * 4];
  const float scale = scale_p[0];
  __syncthreads();

  float pj[32];
  float mx = -1e30f;
#pragma unroll
  for (int jj = 0; jj < 32; ++jj) {
    int j = jj * 16 + l;
    const float* kr = &Kh[j * 32];
    int sw = j & 7;
    float s = 0.f;
#pragma unroll
    for (int p = 0; p < 8; ++p) {
      f32x4 kv = *(const f32x4*)&kr[(p ^ sw) * 4];
      s += kv.x * qr[p].x + kv.y * qr[p].y + kv.z * qr[p].z + kv.w * qr[p].w;
    }
    s *= scale;
    pj[jj] = s;
    mx = fmaxf(mx, s);
  }
#pragma unroll
  for (int o = 1; o < 16; o <<= 1) mx = fmaxf(mx, __shfl_xor(mx, o, 16));
  float sum = 0.f;
#pragma unroll
  for (int jj = 0; jj < 32; ++jj) {
    float e = __expf(pj[jj] - mx);
    pj[jj] = e;
    sum += e;
  }
#pragma unroll
  for (int o = 1; o < 16; o <<= 1) sum += __shfl_xor(sum, o, 16);
  float inv = 1.f / sum;
#pragma unroll
  for (int jj = 0; jj < 32; ++jj)
    pb[qi * 512 + jj * 16 + l] = f2bf(pj[jj] * inv);
  __syncthreads();

  // PV: thread (qi, d-pair l): d0 = 2l
  float m0 = 0.f, m1 = 0.f;
  const unsigned short* pq = &pb[qi * 512];
  for (int j = 0; j < 512; ++j) {
    float p = bf2f(pq[j]);
    int chs = (l >> 1) ^ (j & 7);
    const float* vr = &Vh[j * 32 + chs * 4 + ((2 * l) & 3)];
    m0 += p * vr[0];
    m1 += p * vr[1];
  }
  float* mo = &msgs[(size_t)(q0 + qi) * 256 + h * 32 + 2 * l];
  mo[0] = m0;
  mo[1] = m1;
}

// ---------------------------------------------------------------------------
// Out-proj + residual + LayerNorm. Block per 8 nodes (amortizes wo reads).
// ---------------------------------------------------------------------------
__global__ __launch_bounds__(256) void outln_kernel(
    const float* __restrict__ msgs, const float* __restrict__ nodes,
    const float* __restrict__ woT, const float* __restrict__ bo,
    const float* __restrict__ lng, const float* __restrict__ lnb,
    float* __restrict__ enh)
{
  const int blk = blockIdx.x;
  const int co = threadIdx.x;
  __shared__ float ms[8][256];
  __shared__ float red1[8][4], red2[8][4];
  for (int i = co; i < 2048; i += 256)
    ms[i >> 8][i & 255] = msgs[blk * 2048 + i];
  __syncthreads();
  float yv[8];
  float bo_ = bo[co];
#pragma unroll
  for (int r = 0; r < 8; ++r)
    yv[r] = nodes[(size_t)(blk * 8 + r) * 256 + co] + bo_;
  for (int ci = 0; ci < 256; ++ci) {
    float w = woT[ci * 256 + co];
#pragma unroll
    for (int r = 0; r < 8; ++r) yv[r] += ms[r][ci] * w;
  }
  const int wv = co >> 6, lane = co & 63;
#pragma unroll
  for (int r = 0; r < 8; ++r) {
    float s1 = yv[r], s2 = yv[r] * yv[r];
#pragma unroll
    for (int o = 1; o < 64; o <<= 1) {
      s1 += __shfl_xor(s1, o);
      s2 += __shfl_xor(s2, o);
    }
    if (lane == 0) { red1[r][wv] = s1; red2[r][wv] = s2; }
  }
  __syncthreads();
  float lg = lng[co], lb = lnb[co];
#pragma unroll
  for (int r = 0; r < 8; ++r) {
    float S1 = red1[r][0] + red1[r][1] + red1[r][2] + red1[r][3];
    float S2 = red2[r][0] + red2[r][1] + red2[r][2] + red2[r][3];
    float mu = S1 * (1.f / 256.f);
    float var = S2 * (1.f / 256.f) - mu * mu;
    enh[(size_t)(blk * 8 + r) * 256 + co] =
        (yv[r] - mu) * rsqrtf(var + EPSV) * lg + lb;
  }
}

// ---------------------------------------------------------------------------
// Per-batch pooling + rec 1x1 conv + BN2 -> yfin[b][c]. Block per batch.
// ---------------------------------------------------------------------------
__global__ __launch_bounds__(256) void final_kernel(
    const float* __restrict__ enh, const float* __restrict__ recT,
    const float* __restrict__ recb,
    const float* __restrict__ bn2g, const float* __restrict__ bn2b,
    const float* __restrict__ bn2m, const float* __restrict__ bn2v,
    float* __restrict__ yfin)
{
  const int b = blockIdx.x;
  const int tid = threadIdx.x;
  const int wv = tid >> 6, l = tid & 63;
  __shared__ float rm[32], wts[32], wgt[256];
  for (int kk = wv; kk < 32; kk += 4) {
    const float* er = enh + (size_t)(b * 32 + kk) * 256;
    float s = er[l] + er[l + 64] + er[l + 128] + er[l + 192];
#pragma unroll
    for (int o = 1; o < 64; o <<= 1) s += __shfl_xor(s, o);
    if (l == 0) rm[kk] = s * (1.f / 256.f);
  }
  __syncthreads();
  if (tid < 32) {
    float m = rm[tid];
    float mx = m;
#pragma unroll
    for (int o = 1; o < 32; o <<= 1) mx = fmaxf(mx, __shfl_xor(mx, o, 32));
    float e = __expf(m - mx);
    float sm = e;
#pragma unroll
    for (int o = 1; o < 32; o <<= 1) sm += __shfl_xor(sm, o, 32);
    wts[tid] = e / sm;
  }
  __syncthreads();
  float wsum = 0.f;
  for (int kk = 0; kk < 32; ++kk)
    wsum += enh[(size_t)(b * 32 + kk) * 256 + tid] * wts[kk];
  wgt[tid] = wsum;
  __syncthreads();
  const int co = tid;
  float yv = recb[co];
  for (int ci = 0; ci < 256; ++ci)
    yv += wgt[ci] * recT[ci * 256 + co];
  float s = bn2g[co] / sqrtf(bn2v[co] + EPSV);
  yfin[b * 256 + co] = yv * s + (bn2b[co] - bn2m[co] * s);
}

// ---------------------------------------------------------------------------
// out = x + yfin[b][c] broadcast. Block per (b,c) plane (6400 f32 = 1600 f4).
// ---------------------------------------------------------------------------
__global__ __launch_bounds__(256) void add_kernel(
    const float* __restrict__ x, const float* __restrict__ yfin,
    float* __restrict__ out)
{
  const int bc = blockIdx.x;
  const float a = yfin[bc];
  const f32x4* xp = (const f32x4*)(x + (size_t)bc * 6400);
  f32x4* op = (f32x4*)(out + (size_t)bc * 6400);
  for (int i = threadIdx.x; i < 1600; i += 256) {
    f32x4 v = xp[i];
    v.x += a; v.y += a; v.z += a; v.w += a;
    op[i] = v;
  }
}

extern "C" void kernel_launch(void* const* d_in, const int* in_sizes, int n_in,
                              void* d_out, int out_size, void* d_ws, size_t ws_size,
                              hipStream_t stream)
{
  const float* x      = (const float*)d_in[0];
  const float* boxes  = (const float*)d_in[1];
  const float* conv_w = (const float*)d_in[2];
  const float* conv_b = (const float*)d_in[3];
  const float* bn1g   = (const float*)d_in[4];
  const float* bn1b   = (const float*)d_in[5];
  const float* bn1m   = (const float*)d_in[6];
  const float* bn1v   = (const float*)d_in[7];
  const float* wq     = (const float*)d_in[8];
  const float* bq     = (const float*)d_in[9];
  const float* wk     = (const float*)d_in[10];
  const float* bkp    = (const float*)d_in[11];
  const float* wv     = (const float*)d_in[12];
  const float* bv     = (const float*)d_in[13];
  const float* scale  = (const float*)d_in[14];
  const float* wo     = (const float*)d_in[15];
  const float* bo     = (const float*)d_in[16];
  const float* lng    = (const float*)d_in[17];
  const float* lnb    = (const float*)d_in[18];
  const float* rec_w  = (const float*)d_in[19];
  const float* rec_b  = (const float*)d_in[20];
  const float* bn2g   = (const float*)d_in[21];
  const float* bn2b   = (const float*)d_in[22];
  const float* bn2m   = (const float*)d_in[23];
  const float* bn2v   = (const float*)d_in[24];
  float* out = (float*)d_out;

  char* ws = (char*)d_ws;
  unsigned short* Wr = (unsigned short*)(ws);                // 1,179,648 B
  float* wT    = (float*)(ws + 53608448);                    // 1,310,720 B
  float* nodes = (float*)(ws + 54919168);
  float* qb    = nodes + 131072;
  float* kb    = qb + 131072;
  float* vb    = kb + 131072;
  float* enh   = vb + 131072;
  float* yfin  = enh + 131072;                               // 16 KB
  float* msgs  = yfin + 4096;                                // 512 KB

  // xin (NHWC bf16, 52.4 MB) + 1KB zero pad live in d_out scratch — fully
  // consumed by roiconv before add_kernel overwrites d_out. Deterministic:
  // the pad is re-zeroed by prep_fused every call.
  unsigned short* xin = (unsigned short*)d_out;
  float* zpad = (float*)((char*)d_out + 52428800);

  hipLaunchKernelGGL(prep_fused_kernel, dim3(4864), dim3(256), 0, stream,
                     x, xin, conv_w, Wr, zpad, wq, wk, wv, wo, rec_w, wT);
  hipLaunchKernelGGL(roiconv_kernel, dim3(512), dim3(256), 0, stream,
                     xin, boxes, conv_b, bn1g, bn1b, bn1m, bn1v, Wr, nodes);
  hipLaunchKernelGGL(qkv_kernel, dim3(128), dim3(256), 0, stream,
                     nodes, wT, bq, bkp, bv, qb, kb, vb);
  hipLaunchKernelGGL(attn_mh_kernel, dim3(256), dim3(256), 0, stream,
                     qb, kb, vb, scale, msgs);
  hipLaunchKernelGGL(outln_kernel, dim3(64), dim3(256), 0, stream,
                     msgs, nodes, wT + 3 * 65536, bo, lng, lnb, enh);
  hipLaunchKernelGGL(final_kernel, dim3(16), dim3(256), 0, stream,
                     enh, wT + 4 * 65536, rec_b, bn2g, bn2b, bn2m, bn2v, yfin);
  hipLaunchKernelGGL(add_kernel, dim3(4096), dim3(256), 0, stream, x, yfin, out);
}

// Round 9
// 182.235 us; speedup vs baseline: 2.5952x; 1.0242x over previous
//
#include <hip/hip_runtime.h>

#define EPSV 1e-5f

typedef __attribute__((ext_vector_type(8))) short short8v;
typedef __attribute__((ext_vector_type(4))) float f32x4;

static __device__ __forceinline__ unsigned short f2bf(float f) {
  unsigned int u = __float_as_uint(f);
  u += 0x7fff + ((u >> 16) & 1);
  return (unsigned short)(u >> 16);
}
static __device__ __forceinline__ float bf2f(unsigned short h) {
  return __uint_as_float(((unsigned int)h) << 16);
}

// async global->LDS 16B: dest = wave-uniform base + lane*16 (linear)
static __device__ __forceinline__ void glds16(const void* g, void* l) {
  __builtin_amdgcn_global_load_lds(
      (const __attribute__((address_space(1))) void*)g,
      (__attribute__((address_space(3))) void*)l, 16, 0, 0);
}

// ---------------------------------------------------------------------------
// Fused prep: blocks [0,1280) NCHW->NHWC bf16; [1280,3584) conv-w reorder
// (+zpad zero); [3584,4864) GAT weight transposes.
// ---------------------------------------------------------------------------
__global__ __launch_bounds__(256) void prep_fused_kernel(
    const float* __restrict__ x, unsigned short* __restrict__ xin,
    const float* __restrict__ cw, unsigned short* __restrict__ Wr,
    float* __restrict__ zpad,
    const float* __restrict__ wq, const float* __restrict__ wk,
    const float* __restrict__ wv, const float* __restrict__ wo,
    const float* __restrict__ rec, float* __restrict__ wT)
{
  __shared__ unsigned short t[80 * 257];
  const int bid = blockIdx.x;
  if (bid < 1280) {
    int b = bid / 80, y = bid - b * 80;
    const float* src = x + (size_t)b * 256 * 6400 + y * 80;
    for (int e = threadIdx.x; e < 256 * 20; e += 256) {
      int c = e / 20;
      int px4 = e - c * 20;
      f32x4 v = *(const f32x4*)&src[(size_t)c * 6400 + px4 * 4];
#pragma unroll
      for (int j = 0; j < 4; ++j)
        t[(px4 * 4 + j) * 257 + c] = f2bf(v[j]);
    }
    __syncthreads();
    unsigned short* dst = xin + (size_t)bid * 80 * 256;
    for (int e = threadIdx.x; e < 80 * 32; e += 256) {
      int px = e >> 5;
      int c8 = e & 31;
      short8v v;
#pragma unroll
      for (int j = 0; j < 8; ++j) v[j] = t[px * 257 + c8 * 8 + j];
      *(short8v*)&dst[px * 256 + c8 * 8] = v;
    }
  } else if (bid < 3584) {
    if (bid == 1280) zpad[threadIdx.x] = 0.f;
    int idx = (bid - 1280) * 256 + threadIdx.x;
    int cil = idx & 31;
    int rest = idx >> 5;
    int co = rest & 255;
    int tcc = rest >> 8;
    int cc = tcc & 7;
    int tt = tcc >> 3;
    int dy = tt / 3, dx = tt - dy * 3;
    int ci = cc * 32 + cil;
    Wr[idx] = f2bf(cw[((co * 256 + ci) * 3 + dy) * 3 + dx]);
  } else {
    int idx = (bid - 3584) * 256 + threadIdx.x;
    int m = idx >> 16;
    int e = idx & 65535;
    int ci = e >> 8, co = e & 255;
    const float* src = (m == 0) ? wq : (m == 1) ? wk : (m == 2) ? wv
                     : (m == 3) ? wo : rec;
    wT[idx] = src[co * 256 + ci];
  }
}

// ---------------------------------------------------------------------------
// Fused direct conv@roi-pixels + BN + SiLU + bilinear avg -> nodes[512][256].
// Block per NODE PAIR: 512 thr / 8 waves = 2(node) x 4(co64). M=128 corner
// px, N=256 co, K=9x256. W staged once per step, SHARED by both nodes ->
// per-CU L2 staging traffic halves vs 1-node blocks. 3-deep buffer rotation
// (buf = t%3), counted s_waitcnt vmcnt(3) + raw s_barrier: step+1's loads
// stay in flight across barriers with 2 full MFMA-steps to complete.
// ---------------------------------------------------------------------------
__global__ __launch_bounds__(512, 1) void roiconv_kernel(
    const unsigned short* __restrict__ xin,   // zpad zeros at byte 52428800
    const float* __restrict__ boxes,
    const float* __restrict__ convb,
    const float* __restrict__ bn1g, const float* __restrict__ bn1b,
    const float* __restrict__ bn1m, const float* __restrict__ bn1v,
    const unsigned short* __restrict__ Wr,
    float* __restrict__ nodes)
{
  const int bid = blockIdx.x;
  const int pr = (bid & 7) * 32 + (bid >> 3);  // XCD-bijective (256%8==0)
  const int tid = threadIdx.x;
  const int nd = tid >> 8;                      // this thread's node (0/1)
  const int n = pr * 2 + nd;
  const int b = n >> 5;
  const int w = tid >> 6, lane = tid & 63;
  const int bq = lane >> 4, r16 = lane & 15;
  const int wr = w >> 2, wc = w & 3;            // wave: node, co-64 group

  // IN bufs: 3 x 8192 @ 0/8192/16384; W bufs: 3 x 16384 @ 24576/40960/57344;
  // wcoef[128] @ 73728. Epilogue bf16 ep[128][264] = 67584B reuses 0..67583.
  __shared__ __align__(16) char lds[74240];
  float* wcoef = (float*)(lds + 73728);
  const int INB = 0, WB = 24576;

  // ---- geometry for this thread's corner pixel pc = (tid>>2)&63 ----
  const int pc = (tid >> 2) & 63;
  const float* bx = boxes + n * 4;
  float x1 = bx[0] * 79.f, y1 = bx[1] * 79.f, x2 = bx[2] * 79.f, y2 = bx[3] * 79.f;
  float rwd = fmaxf(x2 - x1, 1.f), rh = fmaxf(y2 - y1, 1.f);
  int s = pc >> 2;
  int sy = s >> 2, sx = s & 3;
  float yy = y1 + (sy + 0.5f) * 0.25f * rh;
  float xx = x1 + (sx + 0.5f) * 0.25f * rwd;
  bool valid = (yy >= -1.f) && (yy <= 80.f) && (xx >= -1.f) && (xx <= 80.f);
  float yc = fminf(fmaxf(yy, 0.f), 79.f), xc = fminf(fmaxf(xx, 0.f), 79.f);
  float y0f = floorf(yc), x0f = floorf(xc);
  int y0i = (int)y0f, x0i = (int)x0f;
  int y1i = min(y0i + 1, 79), x1i = min(x0i + 1, 79);
  float ly = yc - y0f, lx = xc - x0f, hy = 1.f - ly, hx = 1.f - lx;
  int py = (pc & 2) ? y1i : y0i;
  int pxx = (pc & 1) ? x1i : x0i;
  if ((tid & 3) == 0)
    wcoef[tid >> 2] = ((pc & 2) ? ly : hy) * ((pc & 1) ? lx : hx) *
                      (valid ? 0.0625f : 0.f);

  // ---- staging source offsets (bits 1-2 of pc drive both sides) ----
  const int chunk = (tid & 3) ^ ((pc >> 1) & 3);
  unsigned ioff[9];
#pragma unroll
  for (int t = 0; t < 9; ++t) {
    int dy = t / 3, dx = t - dy * 3;
    int cy = py + dy - 1, cx = pxx + dx - 1;
    bool ok = ((unsigned)cy < 80u) && ((unsigned)cx < 80u);
    ioff[t] = ok ? (unsigned)((((b * 80 + cy) * 80 + cx) * 256 + chunk * 8) * 2)
                 : 52428800u;
  }
  unsigned woff[2];
#pragma unroll
  for (int i = 0; i < 2; ++i) {
    int s2 = tid + (i << 9);
    int wco = s2 >> 2;
    int wch = (s2 & 3) ^ ((wco >> 1) & 3);
    woff[i] = (unsigned)((wco * 32 + wch * 8) * 2);
  }
  const int laneoff = r16 * 64 + ((bq ^ ((r16 >> 1) & 3)) << 4);
  const char* xinb = (const char*)xin;
  const char* Wrb = (const char*)Wr;
  const int ldwave = w << 10;                   // w*1024: wave-uniform dest

  f32x4 acc[4][4];
#pragma unroll
  for (int i = 0; i < 4; ++i)
#pragma unroll
    for (int j = 0; j < 4; ++j)
      acc[i][j] = (f32x4){0.f, 0.f, 0.f, 0.f};

  // prologue: issue steps 0 (buf0) and 1 (buf1); 3 issues/thread/step
  glds16(xinb + ioff[0], lds + INB + ldwave);
  glds16(Wrb + woff[0], lds + WB + ldwave);
  glds16(Wrb + woff[1], lds + WB + 8192 + ldwave);
  glds16(xinb + ioff[1], lds + INB + 8192 + ldwave);
  glds16(Wrb + ((size_t)8 << 14) + woff[0], lds + WB + 16384 + ldwave);
  glds16(Wrb + ((size_t)8 << 14) + woff[1], lds + WB + 16384 + 8192 + ldwave);

  for (int cc = 0; cc < 8; ++cc) {
#pragma unroll
    for (int t = 0; t < 9; ++t) {
      const int cb = t % 3;                     // compile-time buffer index
      const char* inb = lds + INB + cb * 8192;
      const char* wb  = lds + WB + cb * 16384;
      // counted wait: keep step+1's 3 loads in flight; tail drains fully
      if (cc == 7 && t == 8)
        asm volatile("s_waitcnt vmcnt(0)" ::: "memory");
      else
        asm volatile("s_waitcnt vmcnt(3)" ::: "memory");
      __builtin_amdgcn_s_barrier();
      __builtin_amdgcn_sched_barrier(0);
      // issue step+2 (buffer (t+2)%3, last read at step-1 -> barrier-ordered)
      if (!(cc == 7 && t >= 7)) {
        const int nt = (t + 2 > 8) ? t - 7 : t + 2;   // compile-time
        const int nb = nt % 3;
        const int ncc = cc + (t >= 7 ? 1 : 0);
        char* innx = lds + INB + nb * 8192;
        char* wbn  = lds + WB + nb * 16384;
        glds16(xinb + ioff[nt] + ncc * 64, innx + ldwave);
        const char* wg = Wrb + ((size_t)(nt * 8 + ncc) << 14);
        glds16(wg + woff[0], wbn + ldwave);
        glds16(wg + woff[1], wbn + 8192 + ldwave);
      }
      const char* pa = inb + wr * 4096 + laneoff;
      const char* pw = wb + wc * 4096 + laneoff;
      short8v af0 = *(const short8v*)(pa);
      short8v af1 = *(const short8v*)(pa + 1024);
      short8v af2 = *(const short8v*)(pa + 2048);
      short8v af3 = *(const short8v*)(pa + 3072);
      short8v wf0 = *(const short8v*)(pw);
      short8v wf1 = *(const short8v*)(pw + 1024);
      short8v wf2 = *(const short8v*)(pw + 2048);
      short8v wf3 = *(const short8v*)(pw + 3072);
      __builtin_amdgcn_s_setprio(1);
      acc[0][0] = __builtin_amdgcn_mfma_f32_16x16x32_bf16(af0, wf0, acc[0][0], 0, 0, 0);
      acc[0][1] = __builtin_amdgcn_mfma_f32_16x16x32_bf16(af0, wf1, acc[0][1], 0, 0, 0);
      acc[0][2] = __builtin_amdgcn_mfma_f32_16x16x32_bf16(af0, wf2, acc[0][2], 0, 0, 0);
      acc[0][3] = __builtin_amdgcn_mfma_f32_16x16x32_bf16(af0, wf3, acc[0][3], 0, 0, 0);
      acc[1][0] = __builtin_amdgcn_mfma_f32_16x16x32_bf16(af1, wf0, acc[1][0], 0, 0, 0);
      acc[1][1] = __builtin_amdgcn_mfma_f32_16x16x32_bf16(af1, wf1, acc[1][1], 0, 0, 0);
      acc[1][2] = __builtin_amdgcn_mfma_f32_16x16x32_bf16(af1, wf2, acc[1][2], 0, 0, 0);
      acc[1][3] = __builtin_amdgcn_mfma_f32_16x16x32_bf16(af1, wf3, acc[1][3], 0, 0, 0);
      acc[2][0] = __builtin_amdgcn_mfma_f32_16x16x32_bf16(af2, wf0, acc[2][0], 0, 0, 0);
      acc[2][1] = __builtin_amdgcn_mfma_f32_16x16x32_bf16(af2, wf1, acc[2][1], 0, 0, 0);
      acc[2][2] = __builtin_amdgcn_mfma_f32_16x16x32_bf16(af2, wf2, acc[2][2], 0, 0, 0);
      acc[2][3] = __builtin_amdgcn_mfma_f32_16x16x32_bf16(af2, wf3, acc[2][3], 0, 0, 0);
      acc[3][0] = __builtin_amdgcn_mfma_f32_16x16x32_bf16(af3, wf0, acc[3][0], 0, 0, 0);
      acc[3][1] = __builtin_amdgcn_mfma_f32_16x16x32_bf16(af3, wf1, acc[3][1], 0, 0, 0);
      acc[3][2] = __builtin_amdgcn_mfma_f32_16x16x32_bf16(af3, wf2, acc[3][2], 0, 0, 0);
      acc[3][3] = __builtin_amdgcn_mfma_f32_16x16x32_bf16(af3, wf3, acc[3][3], 0, 0, 0);
      __builtin_amdgcn_s_setprio(0);
    }
  }
  __syncthreads();

  // epilogue: bias+BN+SiLU -> bf16 ep[128][264]; then bilinear combine (f32)
  unsigned short* ep = (unsigned short*)lds;
#pragma unroll
  for (int cf = 0; cf < 4; ++cf) {
    int co = wc * 64 + cf * 16 + r16;
    float sc = bn1g[co] / sqrtf(bn1v[co] + EPSV);
    float sh = bn1b[co] - bn1m[co] * sc;
    float cb = convb[co];
#pragma unroll
    for (int mf = 0; mf < 4; ++mf) {
#pragma unroll
      for (int rg = 0; rg < 4; ++rg) {
        int pxo = wr * 64 + mf * 16 + bq * 4 + rg;  // D row (m89)
        float v = (acc[mf][cf][rg] + cb) * sc + sh;
        v = v / (1.f + __expf(-v));                 // SiLU
        ep[pxo * 264 + co] = f2bf(v);
      }
    }
  }
  __syncthreads();
  const int c = tid & 255;
  float val = 0.f;
#pragma unroll
  for (int p = 0; p < 64; ++p)
    val += wcoef[nd * 64 + p] * bf2f(ep[(nd * 64 + p) * 264 + c]);
  nodes[n * 256 + c] = val;
}

// ---------------------------------------------------------------------------
// q,k,v projections. Block handles 4 nodes (grid 128); thread = out channel.
// ---------------------------------------------------------------------------
__global__ __launch_bounds__(256) void qkv_kernel(
    const float* __restrict__ nodes, const float* __restrict__ wT,
    const float* __restrict__ bq, const float* __restrict__ bk,
    const float* __restrict__ bv,
    float* __restrict__ q, float* __restrict__ k, float* __restrict__ v)
{
  const int blk = blockIdx.x;
  const int co = threadIdx.x;
  __shared__ float nd[4][256];
  for (int i = threadIdx.x; i < 1024; i += 256)
    nd[i >> 8][i & 255] = nodes[blk * 1024 + i];
  __syncthreads();
  float aq[4] = {0, 0, 0, 0};
  float ak[4] = {0, 0, 0, 0};
  float av[4] = {0, 0, 0, 0};
  const float* wqT = wT;
  const float* wkT = wT + 65536;
  const float* wvT = wT + 131072;
  for (int ci = 0; ci < 256; ++ci) {
    float wq_ = wqT[ci * 256 + co];
    float wk_ = wkT[ci * 256 + co];
    float wv_ = wvT[ci * 256 + co];
#pragma unroll
    for (int r = 0; r < 4; ++r) {
      float nv = nd[r][ci];
      aq[r] += nv * wq_;
      ak[r] += nv * wk_;
      av[r] += nv * wv_;
    }
  }
  float bq_ = bq[co], bk_ = bk[co], bv_ = bv[co];
#pragma unroll
  for (int r = 0; r < 4; ++r) {
    int n = blk * 4 + r;
    q[n * 256 + co] = aq[r] + bq_;
    k[n * 256 + co] = ak[r] + bk_;
    v[n * 256 + co] = av[r] + bv_;
  }
}

// ---------------------------------------------------------------------------
// Multi-head attention core: block per (head, 16-query chunk) = 256 blocks.
// K_h, V_h staged in LDS [512][32] f32 with chunk-XOR swizzle (~2-way free).
// Scores in regs (32/thread), softmax via 16-wide shfl, P bf16 in LDS,
// PV per (query, d-pair) -> msgs[512][256].
// ---------------------------------------------------------------------------
__global__ __launch_bounds__(256) void attn_mh_kernel(
    const float* __restrict__ q, const float* __restrict__ k,
    const float* __restrict__ v, const float* __restrict__ scale_p,
    float* __restrict__ msgs)
{
  const int bid = blockIdx.x;
  const int h = bid & 7, qc = bid >> 3;       // qc 0..31
  const int q0 = qc * 16;
  const int tid = threadIdx.x;
  __shared__ __align__(16) float Kh[512 * 32];
  __shared__ __align__(16) float Vh[512 * 32];
  __shared__ unsigned short pb[16 * 512];

  for (int idx = tid; idx < 4096; idx += 256) {
    int j = idx >> 3, part = idx & 7;
    int chs = part ^ (j & 7);
    *(f32x4*)&Kh[j * 32 + chs * 4] =
        *(const f32x4*)&k[(size_t)j * 256 + h * 32 + part * 4];
    *(f32x4*)&Vh[j * 32 + chs * 4] =
        *(const f32x4*)&v[(size_t)j * 256 + h * 32 + part * 4];
  }
  const int qi = tid >> 4, l = tid & 15;
  f32x4 qr[8];
#pragma unroll
  for (int p = 0; p < 8; ++p)
    qr[p] = *(const f32x4*)&q[(size_t)(q0 + qi) * 256 + h * 32 + p * 4];
  const float scale = scale_p[0];
  __syncthreads();

  float pj[32];
  float mx = -1e30f;
#pragma unroll
  for (int jj = 0; jj < 32; ++jj) {
    int j = jj * 16 + l;
    const float* kr = &Kh[j * 32];
    int sw = j & 7;
    float s = 0.f;
#pragma unroll
    for (int p = 0; p < 8; ++p) {
      f32x4 kv = *(const f32x4*)&kr[(p ^ sw) * 4];
      s += kv.x * qr[p].x + kv.y * qr[p].y + kv.z * qr[p].z + kv.w * qr[p].w;
    }
    s *= scale;
    pj[jj] = s;
    mx = fmaxf(mx, s);
  }
#pragma unroll
  for (int o = 1; o < 16; o <<= 1) mx = fmaxf(mx, __shfl_xor(mx, o, 16));
  float sum = 0.f;
#pragma unroll
  for (int jj = 0; jj < 32; ++jj) {
    float e = __expf(pj[jj] - mx);
    pj[jj] = e;
    sum += e;
  }
#pragma unroll
  for (int o = 1; o < 16; o <<= 1) sum += __shfl_xor(sum, o, 16);
  float inv = 1.f / sum;
#pragma unroll
  for (int jj = 0; jj < 32; ++jj)
    pb[qi * 512 + jj * 16 + l] = f2bf(pj[jj] * inv);
  __syncthreads();

  // PV: thread (qi, d-pair l): d0 = 2l
  float m0 = 0.f, m1 = 0.f;
  const unsigned short* pq = &pb[qi * 512];
  for (int j = 0; j < 512; ++j) {
    float p = bf2f(pq[j]);
    int chs = (l >> 1) ^ (j & 7);
    const float* vr = &Vh[j * 32 + chs * 4 + ((2 * l) & 3)];
    m0 += p * vr[0];
    m1 += p * vr[1];
  }
  float* mo = &msgs[(size_t)(q0 + qi) * 256 + h * 32 + 2 * l];
  mo[0] = m0;
  mo[1] = m1;
}

// ---------------------------------------------------------------------------
// Out-proj + residual + LayerNorm. Block per 8 nodes (amortizes wo reads).
// ---------------------------------------------------------------------------
__global__ __launch_bounds__(256) void outln_kernel(
    const float* __restrict__ msgs, const float* __restrict__ nodes,
    const float* __restrict__ woT, const float* __restrict__ bo,
    const float* __restrict__ lng, const float* __restrict__ lnb,
    float* __restrict__ enh)
{
  const int blk = blockIdx.x;
  const int co = threadIdx.x;
  __shared__ float ms[8][256];
  __shared__ float red1[8][4], red2[8][4];
  for (int i = co; i < 2048; i += 256)
    ms[i >> 8][i & 255] = msgs[blk * 2048 + i];
  __syncthreads();
  float yv[8];
  float bo_ = bo[co];
#pragma unroll
  for (int r = 0; r < 8; ++r)
    yv[r] = nodes[(size_t)(blk * 8 + r) * 256 + co] + bo_;
  for (int ci = 0; ci < 256; ++ci) {
    float w = woT[ci * 256 + co];
#pragma unroll
    for (int r = 0; r < 8; ++r) yv[r] += ms[r][ci] * w;
  }
  const int wv = co >> 6, lane = co & 63;
#pragma unroll
  for (int r = 0; r < 8; ++r) {
    float s1 = yv[r], s2 = yv[r] * yv[r];
#pragma unroll
    for (int o = 1; o < 64; o <<= 1) {
      s1 += __shfl_xor(s1, o);
      s2 += __shfl_xor(s2, o);
    }
    if (lane == 0) { red1[r][wv] = s1; red2[r][wv] = s2; }
  }
  __syncthreads();
  float lg = lng[co], lb = lnb[co];
#pragma unroll
  for (int r = 0; r < 8; ++r) {
    float S1 = red1[r][0] + red1[r][1] + red1[r][2] + red1[r][3];
    float S2 = red2[r][0] + red2[r][1] + red2[r][2] + red2[r][3];
    float mu = S1 * (1.f / 256.f);
    float var = S2 * (1.f / 256.f) - mu * mu;
    enh[(size_t)(blk * 8 + r) * 256 + co] =
        (yv[r] - mu) * rsqrtf(var + EPSV) * lg + lb;
  }
}

// ---------------------------------------------------------------------------
// Per-batch pooling + rec 1x1 conv + BN2 -> yfin[b][c]. Block per batch.
// ---------------------------------------------------------------------------
__global__ __launch_bounds__(256) void final_kernel(
    const float* __restrict__ enh, const float* __restrict__ recT,
    const float* __restrict__ recb,
    const float* __restrict__ bn2g, const float* __restrict__ bn2b,
    const float* __restrict__ bn2m, const float* __restrict__ bn2v,
    float* __restrict__ yfin)
{
  const int b = blockIdx.x;
  const int tid = threadIdx.x;
  const int wv = tid >> 6, l = tid & 63;
  __shared__ float rm[32], wts[32], wgt[256];
  for (int kk = wv; kk < 32; kk += 4) {
    const float* er = enh + (size_t)(b * 32 + kk) * 256;
    float s = er[l] + er[l + 64] + er[l + 128] + er[l + 192];
#pragma unroll
    for (int o = 1; o < 64; o <<= 1) s += __shfl_xor(s, o);
    if (l == 0) rm[kk] = s * (1.f / 256.f);
  }
  __syncthreads();
  if (tid < 32) {
    float m = rm[tid];
    float mx = m;
#pragma unroll
    for (int o = 1; o < 32; o <<= 1) mx = fmaxf(mx, __shfl_xor(mx, o, 32));
    float e = __expf(m - mx);
    float sm = e;
#pragma unroll
    for (int o = 1; o < 32; o <<= 1) sm += __shfl_xor(sm, o, 32);
    wts[tid] = e / sm;
  }
  __syncthreads();
  float wsum = 0.f;
  for (int kk = 0; kk < 32; ++kk)
    wsum += enh[(size_t)(b * 32 + kk) * 256 + tid] * wts[kk];
  wgt[tid] = wsum;
  __syncthreads();
  const int co = tid;
  float yv = recb[co];
  for (int ci = 0; ci < 256; ++ci)
    yv += wgt[ci] * recT[ci * 256 + co];
  float s = bn2g[co] / sqrtf(bn2v[co] + EPSV);
  yfin[b * 256 + co] = yv * s + (bn2b[co] - bn2m[co] * s);
}

// ---------------------------------------------------------------------------
// out = x + yfin[b][c] broadcast. Block per (b,c) plane (6400 f32 = 1600 f4).
// ---------------------------------------------------------------------------
__global__ __launch_bounds__(256) void add_kernel(
    const float* __restrict__ x, const float* __restrict__ yfin,
    float* __restrict__ out)
{
  const int bc = blockIdx.x;
  const float a = yfin[bc];
  const f32x4* xp = (const f32x4*)(x + (size_t)bc * 6400);
  f32x4* op = (f32x4*)(out + (size_t)bc * 6400);
  for (int i = threadIdx.x; i < 1600; i += 256) {
    f32x4 v = xp[i];
    v.x += a; v.y += a; v.z += a; v.w += a;
    op[i] = v;
  }
}

extern "C" void kernel_launch(void* const* d_in, const int* in_sizes, int n_in,
                              void* d_out, int out_size, void* d_ws, size_t ws_size,
                              hipStream_t stream)
{
  const float* x      = (const float*)d_in[0];
  const float* boxes  = (const float*)d_in[1];
  const float* conv_w = (const float*)d_in[2];
  const float* conv_b = (const float*)d_in[3];
  const float* bn1g   = (const float*)d_in[4];
  const float* bn1b   = (const float*)d_in[5];
  const float* bn1m   = (const float*)d_in[6];
  const float* bn1v   = (const float*)d_in[7];
  const float* wq     = (const float*)d_in[8];
  const float* bq     = (const float*)d_in[9];
  const float* wk     = (const float*)d_in[10];
  const float* bkp    = (const float*)d_in[11];
  const float* wv     = (const float*)d_in[12];
  const float* bv     = (const float*)d_in[13];
  const float* scale  = (const float*)d_in[14];
  const float* wo     = (const float*)d_in[15];
  const float* bo     = (const float*)d_in[16];
  const float* lng    = (const float*)d_in[17];
  const float* lnb    = (const float*)d_in[18];
  const float* rec_w  = (const float*)d_in[19];
  const float* rec_b  = (const float*)d_in[20];
  const float* bn2g   = (const float*)d_in[21];
  const float* bn2b   = (const float*)d_in[22];
  const float* bn2m   = (const float*)d_in[23];
  const float* bn2v   = (const float*)d_in[24];
  float* out = (float*)d_out;

  char* ws = (char*)d_ws;
  unsigned short* Wr = (unsigned short*)(ws);                // 1,179,648 B
  float* wT    = (float*)(ws + 53608448);                    // 1,310,720 B
  float* nodes = (float*)(ws + 54919168);
  float* qb    = nodes + 131072;
  float* kb    = qb + 131072;
  float* vb    = kb + 131072;
  float* enh   = vb + 131072;
  float* yfin  = enh + 131072;                               // 16 KB
  float* msgs  = yfin + 4096;                                // 512 KB

  // xin (NHWC bf16, 52.4 MB) + 1KB zero pad live in d_out scratch — fully
  // consumed by roiconv before add_kernel overwrites d_out. Deterministic:
  // the pad is re-zeroed by prep_fused every call.
  unsigned short* xin = (unsigned short*)d_out;
  float* zpad = (float*)((char*)d_out + 52428800);

  hipLaunchKernelGGL(prep_fused_kernel, dim3(4864), dim3(256), 0, stream,
                     x, xin, conv_w, Wr, zpad, wq, wk, wv, wo, rec_w, wT);
  hipLaunchKernelGGL(roiconv_kernel, dim3(256), dim3(512), 0, stream,
                     xin, boxes, conv_b, bn1g, bn1b, bn1m, bn1v, Wr, nodes);
  hipLaunchKernelGGL(qkv_kernel, dim3(128), dim3(256), 0, stream,
                     nodes, wT, bq, bkp, bv, qb, kb, vb);
  hipLaunchKernelGGL(attn_mh_kernel, dim3(256), dim3(256), 0, stream,
                     qb, kb, vb, scale, msgs);
  hipLaunchKernelGGL(outln_kernel, dim3(64), dim3(256), 0, stream,
                     msgs, nodes, wT + 3 * 65536, bo, lng, lnb, enh);
  hipLaunchKernelGGL(final_kernel, dim3(16), dim3(256), 0, stream,
                     enh, wT + 4 * 65536, rec_b, bn2g, bn2b, bn2m, bn2v, yfin);
  hipLaunchKernelGGL(add_kernel, dim3(4096), dim3(256), 0, stream, x, yfin, out);
}